// Round 7
// baseline (576.382 us; speedup 1.0000x reference)
//
#include <hip/hip_runtime.h>
#include <stdint.h>
#include <stddef.h>

// ---------------------------------------------------------------------------
// VQ-VAE quantizer, MI355X.  dist(n,k) = ||x||^2 + ||w_k||^2 - 2 x.w_k.
// f16 GEMM (KD=128), fragment-linear A/B, no LDS/barriers in K-loop.
// Refine architecture (R4, proven): per-row threshold T = d1~ + 2E.
//   - every colslice with top1~ <= T contributes its top-1 code as candidate
//   - if any colslice's top2~ <= T -> exact full rescan for the row
//   - candidates resolved by exact fp32 distance + u64 atomicMin key
// R7: gemm regridded to 8 colsplits x 128 rowblocks; per-lane top-2 carried
//     in registers across a 1024-col sweep (scan key wn-2S, xn added at
//     write); ONE butterfly per block.  Tail fused into scatter_qsum.
// ---------------------------------------------------------------------------

#define N_ROWS   16384      // B*H*W = 16*32*32
#define K_CODES  8192
#define C_DIM    128

typedef _Float16 f16x8 __attribute__((ext_vector_type(8)));
typedef float    f32x4 __attribute__((ext_vector_type(4)));

// ---------------- prep: pack encodings -> Ap fragment-linear, xnorm --------
// Ap layout: half Ap[rowtile R=n>>4][kchunk C=c>>5][lane][8]
//   lane = (n&15) + 16*((c&31)>>3), elem j = c&7   (MFMA A-operand order)
__global__ __launch_bounds__(256) void prep_x(const float* __restrict__ enc,
                                              _Float16* __restrict__ Ap,
                                              float* __restrict__ xnorm) {
  __shared__ float t[128][65];
  const int tid = threadIdx.x;
  const int b = blockIdx.x >> 4;
  const int hw0 = (blockIdx.x & 15) << 6;
  #pragma unroll
  for (int i = 0; i < 32; ++i) {
    int idx = i * 256 + tid;
    int c = idx >> 6, hwl = idx & 63;
    t[c][hwl] = enc[((size_t)(b * 128 + c) << 10) + hw0 + hwl];
  }
  __syncthreads();
  const int r = tid >> 2, sub = tid & 3;         // row-in-block, k-chunk
  const int n = (b << 10) + hw0 + r;
  const int R = n >> 4, m = n & 15;
  float s = 0.f;
  #pragma unroll
  for (int q = 0; q < 4; ++q) {
    f16x8 hv;
    #pragma unroll
    for (int e = 0; e < 8; ++e) {
      float v = t[sub * 32 + q * 8 + e][r];
      s += v * v;
      hv[e] = (_Float16)v;
    }
    *(f16x8*)(Ap + ((size_t)(R * 4 + sub) * 64 + (m + 16 * q)) * 8) = hv;
  }
  s += __shfl_xor(s, 1);
  s += __shfl_xor(s, 2);
  if (sub == 0) xnorm[n] = s;
}

// ---------------- prep: pack weight -> Bp fragment-linear, wnorm, wnmax ----
__global__ __launch_bounds__(256) void prep_w(const float* __restrict__ w,
                                              _Float16* __restrict__ Bp,
                                              float* __restrict__ wnorm,
                                              unsigned* __restrict__ wnmax) {
  const int tid = threadIdx.x;
  const int kk = blockIdx.x * 64 + (tid >> 2), sub = tid & 3;
  const int R = kk >> 4, m = kk & 15;
  const float* base = w + (size_t)kk * C_DIM + sub * 32;
  float s = 0.f;
  #pragma unroll
  for (int q = 0; q < 4; ++q) {
    f16x8 hv;
    float4 va = *(const float4*)(base + q * 8);
    float4 vb = *(const float4*)(base + q * 8 + 4);
    float vv[8] = {va.x, va.y, va.z, va.w, vb.x, vb.y, vb.z, vb.w};
    #pragma unroll
    for (int e = 0; e < 8; ++e) { s += vv[e] * vv[e]; hv[e] = (_Float16)vv[e]; }
    *(f16x8*)(Bp + ((size_t)(R * 4 + sub) * 64 + (m + 16 * q)) * 8) = hv;
  }
  s += __shfl_xor(s, 1);
  s += __shfl_xor(s, 2);
  if (sub == 0) {
    wnorm[kk] = s;
    atomicMax(wnmax, __float_as_uint(s));        // s > 0 -> bit-monotone
  }
}

// ---------------- main GEMM + per-(row,colslice) top-2 ---------------------
// Grid (8 colsplits, 128 rowblocks).  Block: 128 rows x 1024 cols swept as
// 8 col-iterations of 128 cols.  Wave tile 32 rows x 128 cols (2ti x 8tj
// MFMA f32_16x16x32_f16).  Per-lane top-2 (8 rows) carried in registers
// across the sweep; scan key = wn - 2S (xn per-row constant, added at
// write; ordering unchanged).  One 16-lane butterfly per block at the end.
__global__ __launch_bounds__(256) void gemm_argmin(
    const _Float16* __restrict__ Ap, const _Float16* __restrict__ Bp,
    const float* __restrict__ xnorm, const float* __restrict__ wnorm,
    float* __restrict__ pd1, unsigned* __restrict__ pc1,
    float* __restrict__ pd2)
{
  const int tid = threadIdx.x;
  const int lane = tid & 63, wave = tid >> 6;
  const int m = lane & 15, q = lane >> 4;
  const int cs = blockIdx.x;                     // col slice (1024 cols)
  const int row0 = blockIdx.y * 128;
  const int Tr = blockIdx.y * 8 + wave * 2;      // wave's 2 row-tiles

  float d1[8], d2[8]; unsigned c1[8];
  #pragma unroll
  for (int r = 0; r < 8; ++r) {
    d1[r] = __builtin_inff(); d2[r] = __builtin_inff(); c1[r] = 0;
  }

  for (int it = 0; it < 8; ++it) {               // ascending cols
    const int T0 = cs * 64 + it * 8;             // col-tile base
    f32x4 acc[2][8];
    #pragma unroll
    for (int ti = 0; ti < 2; ++ti)
      #pragma unroll
      for (int tj = 0; tj < 8; ++tj) acc[ti][tj] = (f32x4){0.f, 0.f, 0.f, 0.f};
    #pragma unroll
    for (int kc = 0; kc < 4; ++kc) {
      f16x8 a0 = *(const f16x8*)(Ap + (((size_t)Tr * 4 + kc) << 9) + (lane << 3));
      f16x8 a1 = *(const f16x8*)(Ap + (((size_t)(Tr + 1) * 4 + kc) << 9) + (lane << 3));
      #pragma unroll
      for (int tj = 0; tj < 8; ++tj) {
        f16x8 b = *(const f16x8*)(Bp + (((size_t)(T0 + tj) * 4 + kc) << 9) + (lane << 3));
        acc[0][tj] = __builtin_amdgcn_mfma_f32_16x16x32_f16(a0, b, acc[0][tj], 0, 0, 0);
        acc[1][tj] = __builtin_amdgcn_mfma_f32_16x16x32_f16(a1, b, acc[1][tj], 0, 0, 0);
      }
    }
    // top-2 update; C/D layout col=lane&15, row=4q+r_ (dtype-independent)
    #pragma unroll
    for (int tj = 0; tj < 8; ++tj) {
      unsigned cc = (unsigned)((T0 + tj) * 16 + m);
      float wn = wnorm[cc];
      #pragma unroll
      for (int ti = 0; ti < 2; ++ti)
        #pragma unroll
        for (int r_ = 0; r_ < 4; ++r_) {
          int r = ti * 4 + r_;
          float dd = fmaf(-2.0f, acc[ti][tj][r_], wn);
          if (dd < d1[r]) { d2[r] = d1[r]; d1[r] = dd; c1[r] = cc; }
          else            { d2[r] = fminf(d2[r], dd); }
        }
    }
  }
  // one 16-lane butterfly per row; lex (d,c) keeps first-min tie rule
  #pragma unroll
  for (int r = 0; r < 8; ++r) {
    float a1v = d1[r], a2v = d2[r]; unsigned ac = c1[r];
    #pragma unroll
    for (int s = 1; s <= 8; s <<= 1) {
      float    o1 = __shfl_xor(a1v, s), o2 = __shfl_xor(a2v, s);
      unsigned oc = (unsigned)__shfl_xor((int)ac, s);
      float n2 = fminf(fminf(a2v, o2), fmaxf(a1v, o1));
      if (o1 < a1v || (o1 == a1v && oc < ac)) { a1v = o1; ac = oc; }
      a2v = n2;
    }
    if (m == 0) {
      int row = row0 + wave * 32 + (r >> 2) * 16 + 4 * q + (r & 3);
      float xn = xnorm[row];
      size_t pi = (size_t)cs * N_ROWS + row;
      pd1[pi] = xn + a1v; pc1[pi] = ac; pd2[pi] = xn + a2v;
    }
  }
}

// ---------------- classify: threshold-collect over 8 colslices -------------
__global__ void merge_classify(const float* __restrict__ pd1,
                               const unsigned* __restrict__ pc1,
                               const float* __restrict__ pd2,
                               const float* __restrict__ xnorm,
                               const unsigned* __restrict__ wnmax,
                               int* __restrict__ ids,
                               unsigned* __restrict__ items,
                               unsigned* __restrict__ icount,
                               int* __restrict__ fulll,
                               unsigned* __restrict__ fcount,
                               float* __restrict__ out_ids) {
  int row = blockIdx.x * 256 + threadIdx.x;
  float d1 = __builtin_inff(); unsigned c1 = 0;
  #pragma unroll
  for (int cb = 0; cb < 8; ++cb) {               // lex (d,c) = first-min rule
    size_t i = (size_t)cb * N_ROWS + row;
    float od = pd1[i]; unsigned oc = pc1[i];
    if (od < d1 || (od == d1 && oc < c1)) { d1 = od; c1 = oc; }
  }
  float wm = __uint_as_float(*wnmax);
  float twoE = 2.0f * (0.0029297f * sqrtf(xnorm[row] * wm) + 2e-4f);
  float T = d1 + twoE;
  bool full = false;
  int nc = 0;
  unsigned cands[6];
  #pragma unroll
  for (int cb = 0; cb < 8; ++cb) {
    size_t i = (size_t)cb * N_ROWS + row;
    if (pd2[i] <= T) { full = true; }
    else if (pd1[i] <= T) {
      if (nc < 6) cands[nc++] = pc1[i];
      else full = true;
    }
  }
  ids[row] = (int)c1;                            // exact if nc==1 && !full
  out_ids[row] = (float)c1;
  if (full) {
    unsigned fi = atomicAdd(fcount, 1u);
    fulll[fi] = row;
  } else if (nc >= 2) {
    unsigned base = atomicAdd(icount, (unsigned)nc);
    for (int i = 0; i < nc; ++i)
      items[base + i] = ((unsigned)row << 13) | cands[i];
  }
}

// ---------------- exact fp32 per-candidate compare (atomicMin key) ---------
__global__ void refine_items(const float* __restrict__ enc,
                             const float* __restrict__ w,
                             const float* __restrict__ wnorm,
                             const unsigned* __restrict__ items,
                             const unsigned* __restrict__ icount,
                             unsigned long long* __restrict__ keys) {
  const unsigned cnt = *icount;
  for (unsigned i = blockIdx.x * blockDim.x + threadIdx.x; i < cnt;
       i += gridDim.x * blockDim.x) {
    unsigned it = items[i];
    int row = (int)(it >> 13), c = (int)(it & 8191u);
    int b = row >> 10, hw = row & 1023;
    const float* xb = enc + ((size_t)b << 17) + hw;
    const float* wk = w + (size_t)c * C_DIM;
    float xn = 0.f, s = 0.f;
    for (int cc = 0; cc < C_DIM; ++cc) {
      float x = xb[(size_t)cc << 10];
      xn += x * x;
      s = fmaf(x, wk[cc], s);
    }
    float d = (xn + wnorm[c]) - 2.0f * s;
    unsigned sb = __float_as_uint(d);
    sb = (sb >> 31) ? ~sb : (sb | 0x80000000u);  // sortable float bits
    unsigned long long key = ((unsigned long long)sb << 32) | (unsigned)c;
    atomicMin(&keys[row], key);                  // tie -> lowest code
  }
}

// ---------------- exact fp32 full rescan, sliced over the codebook ---------
// Work item = (flagged row, 1024-code slice); per-(row,code) fmaf chain
// order bit-identical to R4/R5/R6.  Merges via atomicMin into keys[].
__global__ __launch_bounds__(256) void refine_full(
    const float* __restrict__ enc, const float* __restrict__ w,
    const float* __restrict__ wnorm,
    const int* __restrict__ fulll, const unsigned* __restrict__ fcount,
    unsigned long long* __restrict__ keys) {
  __shared__ __align__(16) float xs[128];
  __shared__ unsigned long long red[4];
  const int tid = threadIdx.x;
  const int lane = tid & 63, wave = tid >> 6;
  const unsigned cnt = *fcount;
  const unsigned nitems = cnt * 8;
  for (unsigned item = blockIdx.x; item < nitems; item += gridDim.x) {
    const int row = fulll[item >> 3];
    const int slice = (int)(item & 7u);
    if (tid < 128)                               // stage x row
      xs[tid] = enc[(((size_t)(row >> 10) * 128 + tid) << 10) + (row & 1023)];
    __syncthreads();
    float xn = 0.f;                              // serial order (R4-identical)
    for (int c = 0; c < 128; ++c) xn += xs[c] * xs[c];
    const int k0 = slice * 1024 + tid * 4;
    float S[4];
    #pragma unroll
    for (int j = 0; j < 4; ++j) S[j] = 0.f;
    for (int c4 = 0; c4 < 32; ++c4) {
      float4 xv = *(const float4*)(&xs[c4 * 4]);
      #pragma unroll
      for (int j = 0; j < 4; ++j) {
        float4 wv = *(const float4*)(w + (size_t)(k0 + j) * C_DIM + c4 * 4);
        S[j] = fmaf(xv.x, wv.x, S[j]);
        S[j] = fmaf(xv.y, wv.y, S[j]);
        S[j] = fmaf(xv.z, wv.z, S[j]);
        S[j] = fmaf(xv.w, wv.w, S[j]);
      }
    }
    unsigned long long best = ~0ull;
    #pragma unroll
    for (int j = 0; j < 4; ++j) {
      float d = (xn + wnorm[k0 + j]) - 2.0f * S[j];
      unsigned sb = __float_as_uint(d);
      sb = (sb >> 31) ? ~sb : (sb | 0x80000000u);
      unsigned long long key = ((unsigned long long)sb << 32) | (unsigned)(k0 + j);
      best = best < key ? best : key;
    }
    #pragma unroll
    for (int s = 1; s <= 32; s <<= 1) {          // 64-lane u64 butterfly
      unsigned long long ok = __shfl_xor(best, s);
      best = ok < best ? ok : best;
    }
    if (lane == 0) red[wave] = best;
    __syncthreads();
    if (tid == 0) {
      unsigned long long bk = red[0];
      #pragma unroll
      for (int wv = 1; wv < 4; ++wv) bk = red[wv] < bk ? red[wv] : bk;
      atomicMin(&keys[row], bk);
    }
    __syncthreads();                             // xs reused next item
  }
}

// ---------------- resolve refined rows from keys ---------------------------
__global__ void resolve_keys(const unsigned long long* __restrict__ keys,
                             int* __restrict__ ids, float* __restrict__ out_ids) {
  int row = blockIdx.x * 256 + threadIdx.x;
  unsigned long long k = keys[row];
  if (k != ~0ull) {
    int c = (int)(unsigned)(k & 0xffffffffu);
    ids[row] = c;
    out_ids[row] = (float)c;
  }
}

// ---------------- fused tail: counts + sums + straight-through q -----------
__global__ void scatter_qsum(const float* __restrict__ enc,
                             const float* __restrict__ w,
                             const int* __restrict__ ids,
                             float* __restrict__ sums,
                             float* __restrict__ counts,
                             float* __restrict__ outq) {
  int e = blockIdx.x * 256 + threadIdx.x;        // linear over enc [B,C,H,W]
  int c = (e >> 10) & 127;
  int b = e >> 17;
  int n = (b << 10) | (e & 1023);
  int id = ids[n];
  float x = enc[e];
  unsafeAtomicAdd(&sums[(size_t)id * C_DIM + c], x);
  if (c == 0) unsafeAtomicAdd(&counts[id], 1.0f);  // once per row n
  float wq = w[(size_t)id * C_DIM + c];
  outq[e] = x + (wq - x);                        // reference rounding order
}

// ---------------- finalize: EMA weight -------------------------------------
__global__ void finalize_w(const float* __restrict__ w,
                           const float* __restrict__ sums,
                           const float* __restrict__ counts,
                           float* __restrict__ outw) {
  int i = blockIdx.x * 256 + threadIdx.x;
  int k = i >> 7;
  const float omd = (float)(1.0 - 0.99);
  float mean = sums[i] / (counts[k] + 1e-12f);
  outw[i] = 0.99f * w[i] + omd * mean;
}

// ---------------------------------------------------------------------------
extern "C" void kernel_launch(void* const* d_in, const int* in_sizes, int n_in,
                              void* d_out, int out_size, void* d_ws, size_t ws_size,
                              hipStream_t stream) {
  const float* enc = (const float*)d_in[0];      // [16,128,32,32]
  const float* w   = (const float*)d_in[1];      // [8192,128]
  float* out = (float*)d_out;
  float* out_ids = out;                          // 16384 (ids as float)
  float* out_q   = out + N_ROWS;                 // 2097152
  float* out_w   = out + N_ROWS + N_ROWS * C_DIM;// 1048576

  char* ws = (char*)d_ws;
  _Float16* Ap  = (_Float16*)(ws);                         //  0 .. 4194304
  _Float16* Bp  = (_Float16*)(ws + 4194304);               //  .. 6291456
  float* xnorm  = (float*)(ws + 6291456);                  //  .. 6356992
  float* wnorm  = (float*)(ws + 6356992);                  //  .. 6389760
  float* pd1    = (float*)(ws + 6389760);                  // 8*16384*4 = 512K
  float* pd2    = (float*)(ws + 10584064);                 //  (slack kept)
  unsigned* pc1 = (unsigned*)(ws + 14778368);
  int* ids      = (int*)(ws + 18972672);
  int* fulll    = (int*)(ws + 19038208);
  unsigned* items = (unsigned*)(ws + 19103744);
  unsigned* wnmax  = (unsigned*)(ws + 20152320);           // ctrl 16 B
  unsigned* icount = (unsigned*)(ws + 20152324);
  unsigned* fcount = (unsigned*)(ws + 20152328);
  float* counts = (float*)(ws + 20152336);
  float* sums   = (float*)(ws + 20185104);
  unsigned long long* keys = (unsigned long long*)(ws + 24379408);
  (void)in_sizes; (void)n_in; (void)out_size; (void)ws_size;

  // zero ctrl+counts+sums, then 0xFF keys (keys sentinel = ~0ull)
  hipMemsetAsync(ws + 20152320, 0, 16 + 32768 + 4194304, stream);
  hipMemsetAsync(ws + 24379408, 0xFF, N_ROWS * 8, stream);

  prep_x<<<256, 256, 0, stream>>>(enc, Ap, xnorm);
  prep_w<<<K_CODES / 64, 256, 0, stream>>>(w, Bp, wnorm, wnmax);
  gemm_argmin<<<dim3(8, N_ROWS / 128), 256, 0, stream>>>(
      Ap, Bp, xnorm, wnorm, pd1, pc1, pd2);
  merge_classify<<<N_ROWS / 256, 256, 0, stream>>>(
      pd1, pc1, pd2, xnorm, wnmax, ids, items, icount, fulll, fcount, out_ids);
  refine_items<<<256, 256, 0, stream>>>(enc, w, wnorm, items, icount, keys);
  refine_full<<<2048, 256, 0, stream>>>(enc, w, wnorm, fulll, fcount, keys);
  resolve_keys<<<N_ROWS / 256, 256, 0, stream>>>(keys, ids, out_ids);
  scatter_qsum<<<(N_ROWS * C_DIM) / 256, 256, 0, stream>>>(enc, w, ids, sums,
                                                           counts, out_q);
  finalize_w<<<(K_CODES * C_DIM) / 256, 256, 0, stream>>>(w, sums, counts, out_w);
}

// Round 8
// 425.990 us; speedup vs baseline: 1.3530x; 1.3530x over previous
//
#include <hip/hip_runtime.h>
#include <stdint.h>
#include <stddef.h>

// ---------------------------------------------------------------------------
// VQ-VAE quantizer, MI355X.  dist(n,k) = ||x||^2 + ||w_k||^2 - 2 x.w_k.
// f16 GEMM (KD=128), fragment-linear A/B, no LDS/barriers in K-loop.
// Refine architecture (R4, proven): per-row threshold T = d1~ + 2E over
// 64 col-GROUPS of 128 codes (R8: granularity decoupled from GEMM grid —
// R7's 1024-col slices inflated full-rescans 8x).
//   - every group with top1~ <= T contributes its top-1 code as candidate
//   - if any group's top2~ <= T -> exact full rescan for the row
//   - candidates resolved by exact fp32 distance + u64 atomicMin key
// R8 also fuses: prep_x+prep_w; refine_items+refine_full; resolve_keys
// into scatter_qsum.  8 dispatches total.
// ---------------------------------------------------------------------------

#define N_ROWS   16384      // B*H*W = 16*32*32
#define K_CODES  8192
#define C_DIM    128

typedef _Float16 f16x8 __attribute__((ext_vector_type(8)));
typedef float    f32x4 __attribute__((ext_vector_type(4)));

// ---------------- fused prep: blocks [0,256) pack x, [256,384) pack w ------
// Ap layout: half Ap[rowtile R=n>>4][kchunk C=c>>5][lane][8]
//   lane = (n&15) + 16*((c&31)>>3), elem j = c&7   (MFMA A-operand order)
__global__ __launch_bounds__(256) void prep(const float* __restrict__ enc,
                                            const float* __restrict__ w,
                                            _Float16* __restrict__ Ap,
                                            _Float16* __restrict__ Bp,
                                            float* __restrict__ xnorm,
                                            float* __restrict__ wnorm,
                                            unsigned* __restrict__ wnmax) {
  __shared__ float t[128][65];
  const int tid = threadIdx.x;
  if (blockIdx.x < 256) {                        // ---- x path
    const int b = blockIdx.x >> 4;
    const int hw0 = (blockIdx.x & 15) << 6;
    #pragma unroll
    for (int i = 0; i < 32; ++i) {
      int idx = i * 256 + tid;
      int c = idx >> 6, hwl = idx & 63;
      t[c][hwl] = enc[((size_t)(b * 128 + c) << 10) + hw0 + hwl];
    }
    __syncthreads();
    const int r = tid >> 2, sub = tid & 3;       // row-in-block, k-chunk
    const int n = (b << 10) + hw0 + r;
    const int R = n >> 4, m = n & 15;
    float s = 0.f;
    #pragma unroll
    for (int q = 0; q < 4; ++q) {
      f16x8 hv;
      #pragma unroll
      for (int e = 0; e < 8; ++e) {
        float v = t[sub * 32 + q * 8 + e][r];
        s += v * v;
        hv[e] = (_Float16)v;
      }
      *(f16x8*)(Ap + ((size_t)(R * 4 + sub) * 64 + (m + 16 * q)) * 8) = hv;
    }
    s += __shfl_xor(s, 1);
    s += __shfl_xor(s, 2);
    if (sub == 0) xnorm[n] = s;
  } else {                                       // ---- w path
    const int kk = (blockIdx.x - 256) * 64 + (tid >> 2), sub = tid & 3;
    const int R = kk >> 4, m = kk & 15;
    const float* base = w + (size_t)kk * C_DIM + sub * 32;
    float s = 0.f;
    #pragma unroll
    for (int q = 0; q < 4; ++q) {
      f16x8 hv;
      float4 va = *(const float4*)(base + q * 8);
      float4 vb = *(const float4*)(base + q * 8 + 4);
      float vv[8] = {va.x, va.y, va.z, va.w, vb.x, vb.y, vb.z, vb.w};
      #pragma unroll
      for (int e = 0; e < 8; ++e) { s += vv[e] * vv[e]; hv[e] = (_Float16)vv[e]; }
      *(f16x8*)(Bp + ((size_t)(R * 4 + sub) * 64 + (m + 16 * q)) * 8) = hv;
    }
    s += __shfl_xor(s, 1);
    s += __shfl_xor(s, 2);
    if (sub == 0) {
      wnorm[kk] = s;
      atomicMax(wnmax, __float_as_uint(s));      // s > 0 -> bit-monotone
    }
  }
}

// ---------------- main GEMM + per-(row,128col-group) top-2 -----------------
// Grid (8 colsplits, 128 rowblocks).  Block: 128 rows x 1024 cols swept as
// 8 col-iterations of 128 cols.  Wave tile 32 rows x 128 cols (2ti x 8tj
// MFMA f32_16x16x32_f16).  A-fragments hoisted (it-invariant).  Top-2 is
// computed FRESH per iteration (group g = cs*8+it) and reduced with one
// 16-lane butterfly -> pd1/pc1/pd2 at 64-group granularity (R6-proven
// classify granularity).  Scan key = wn - 2S; xn added at write.
__global__ __launch_bounds__(256) void gemm_argmin(
    const _Float16* __restrict__ Ap, const _Float16* __restrict__ Bp,
    const float* __restrict__ xnorm, const float* __restrict__ wnorm,
    float* __restrict__ pd1, unsigned* __restrict__ pc1,
    float* __restrict__ pd2)
{
  const int tid = threadIdx.x;
  const int lane = tid & 63, wave = tid >> 6;
  const int m = lane & 15, q = lane >> 4;
  const int cs = blockIdx.x;                     // col slice (1024 cols)
  const int row0 = blockIdx.y * 128;
  const int Tr = blockIdx.y * 8 + wave * 2;      // wave's 2 row-tiles

  f16x8 a0[4], a1[4];                            // it-invariant A fragments
  #pragma unroll
  for (int kc = 0; kc < 4; ++kc) {
    a0[kc] = *(const f16x8*)(Ap + (((size_t)Tr * 4 + kc) << 9) + (lane << 3));
    a1[kc] = *(const f16x8*)(Ap + (((size_t)(Tr + 1) * 4 + kc) << 9) + (lane << 3));
  }

  for (int it = 0; it < 8; ++it) {               // ascending col groups
    const int T0 = cs * 64 + it * 8;             // col-tile base
    const int g = cs * 8 + it;                   // group index [0,64)
    f32x4 acc[2][8];
    #pragma unroll
    for (int ti = 0; ti < 2; ++ti)
      #pragma unroll
      for (int tj = 0; tj < 8; ++tj) acc[ti][tj] = (f32x4){0.f, 0.f, 0.f, 0.f};
    #pragma unroll
    for (int kc = 0; kc < 4; ++kc) {
      #pragma unroll
      for (int tj = 0; tj < 8; ++tj) {
        f16x8 b = *(const f16x8*)(Bp + (((size_t)(T0 + tj) * 4 + kc) << 9) + (lane << 3));
        acc[0][tj] = __builtin_amdgcn_mfma_f32_16x16x32_f16(a0[kc], b, acc[0][tj], 0, 0, 0);
        acc[1][tj] = __builtin_amdgcn_mfma_f32_16x16x32_f16(a1[kc], b, acc[1][tj], 0, 0, 0);
      }
    }
    // fresh top-2 for this group; C/D layout col=lane&15, row=4q+r_
    float d1[8], d2[8]; unsigned c1[8];
    #pragma unroll
    for (int r = 0; r < 8; ++r) {
      d1[r] = __builtin_inff(); d2[r] = __builtin_inff(); c1[r] = 0;
    }
    #pragma unroll
    for (int tj = 0; tj < 8; ++tj) {             // ascending col; tie -> lower
      unsigned cc = (unsigned)((T0 + tj) * 16 + m);
      float wn = wnorm[cc];
      #pragma unroll
      for (int ti = 0; ti < 2; ++ti)
        #pragma unroll
        for (int r_ = 0; r_ < 4; ++r_) {
          int r = ti * 4 + r_;
          float dd = fmaf(-2.0f, acc[ti][tj][r_], wn);
          if (dd < d1[r]) { d2[r] = d1[r]; d1[r] = dd; c1[r] = cc; }
          else            { d2[r] = fminf(d2[r], dd); }
        }
    }
    // one 16-lane butterfly per row; lex (d,c) keeps first-min tie rule
    #pragma unroll
    for (int r = 0; r < 8; ++r) {
      float a1v = d1[r], a2v = d2[r]; unsigned ac = c1[r];
      #pragma unroll
      for (int s = 1; s <= 8; s <<= 1) {
        float    o1 = __shfl_xor(a1v, s), o2 = __shfl_xor(a2v, s);
        unsigned oc = (unsigned)__shfl_xor((int)ac, s);
        float n2 = fminf(fminf(a2v, o2), fmaxf(a1v, o1));
        if (o1 < a1v || (o1 == a1v && oc < ac)) { a1v = o1; ac = oc; }
        a2v = n2;
      }
      if (m == 0) {
        int row = row0 + wave * 32 + (r >> 2) * 16 + 4 * q + (r & 3);
        float xn = xnorm[row];
        size_t pi = (size_t)g * N_ROWS + row;
        pd1[pi] = xn + a1v; pc1[pi] = ac; pd2[pi] = xn + a2v;
      }
    }
  }
}

// ---------------- classify: threshold-collect over 64 groups ---------------
__global__ void merge_classify(const float* __restrict__ pd1,
                               const unsigned* __restrict__ pc1,
                               const float* __restrict__ pd2,
                               const float* __restrict__ xnorm,
                               const unsigned* __restrict__ wnmax,
                               int* __restrict__ ids,
                               unsigned* __restrict__ items,
                               unsigned* __restrict__ icount,
                               int* __restrict__ fulll,
                               unsigned* __restrict__ fcount) {
  int row = blockIdx.x * 256 + threadIdx.x;
  // pass 1: global top-1, 4 independent sub-chains (ILP), lex-combine
  float da = __builtin_inff(), db = __builtin_inff(),
        dc = __builtin_inff(), dd = __builtin_inff();
  unsigned ca = 0, cb_ = 0, cc = 0, cd = 0;
  for (int cb = 0; cb < 64; cb += 4) {
    size_t i0 = (size_t)cb * N_ROWS + row;
    float va = pd1[i0], vb = pd1[i0 + (size_t)N_ROWS],
          vc = pd1[i0 + 2 * (size_t)N_ROWS], vd = pd1[i0 + 3 * (size_t)N_ROWS];
    unsigned ka = pc1[i0], kb = pc1[i0 + (size_t)N_ROWS],
             kc = pc1[i0 + 2 * (size_t)N_ROWS], kd = pc1[i0 + 3 * (size_t)N_ROWS];
    if (va < da || (va == da && ka < ca)) { da = va; ca = ka; }
    if (vb < db || (vb == db && kb < cb_)) { db = vb; cb_ = kb; }
    if (vc < dc || (vc == dc && kc < cc)) { dc = vc; cc = kc; }
    if (vd < dd || (vd == dd && kd < cd)) { dd = vd; cd = kd; }
  }
  float d1 = da; unsigned c1 = ca;
  if (db < d1 || (db == d1 && cb_ < c1)) { d1 = db; c1 = cb_; }
  if (dc < d1 || (dc == d1 && cc < c1)) { d1 = dc; c1 = cc; }
  if (dd < d1 || (dd == d1 && cd < c1)) { d1 = dd; c1 = cd; }

  float wm = __uint_as_float(*wnmax);
  float twoE = 2.0f * (0.0029297f * sqrtf(xnorm[row] * wm) + 2e-4f);
  float T = d1 + twoE;
  bool full = false;
  int nc = 0;
  unsigned cands[6];
  #pragma unroll 4
  for (int cb = 0; cb < 64; ++cb) {
    size_t i = (size_t)cb * N_ROWS + row;
    if (pd2[i] <= T) { full = true; }
    else if (pd1[i] <= T) {
      if (nc < 6) cands[nc++] = pc1[i];
      else full = true;
    }
  }
  ids[row] = (int)c1;                            // exact if nc==1 && !full
  if (full) {
    unsigned fi = atomicAdd(fcount, 1u);
    fulll[fi] = row;
  } else if (nc >= 2) {
    unsigned base = atomicAdd(icount, (unsigned)nc);
    for (int i = 0; i < nc; ++i)
      items[base + i] = ((unsigned)row << 13) | cands[i];
  }
}

// ---------------- fused exact refine: items (phase A) + full (phase B) -----
// Phase A: thread-per-item exact c-vs-c compare.  Phase B: block-per-
// (row, 1024-code slice) exact rescan.  Both merge via atomicMin into
// keys[] (sortable-float<<32 | code); per-(row,code) fmaf order identical
// to the R4..R7-passing kernels.
__global__ __launch_bounds__(256) void refine(
    const float* __restrict__ enc, const float* __restrict__ w,
    const float* __restrict__ wnorm,
    const unsigned* __restrict__ items, const unsigned* __restrict__ icount,
    const int* __restrict__ fulll, const unsigned* __restrict__ fcount,
    unsigned long long* __restrict__ keys) {
  const int tid = threadIdx.x;
  const int lane = tid & 63, wave = tid >> 6;
  // ---- phase A: candidate items
  const unsigned ic = *icount;
  for (unsigned i = blockIdx.x * 256 + tid; i < ic; i += gridDim.x * 256) {
    unsigned it = items[i];
    int row = (int)(it >> 13), c = (int)(it & 8191u);
    int b = row >> 10, hw = row & 1023;
    const float* xb = enc + ((size_t)b << 17) + hw;
    const float* wk = w + (size_t)c * C_DIM;
    float xn = 0.f, s = 0.f;
    for (int cc = 0; cc < C_DIM; ++cc) {
      float x = xb[(size_t)cc << 10];
      xn += x * x;
      s = fmaf(x, wk[cc], s);
    }
    float d = (xn + wnorm[c]) - 2.0f * s;
    unsigned sb = __float_as_uint(d);
    sb = (sb >> 31) ? ~sb : (sb | 0x80000000u);  // sortable float bits
    unsigned long long key = ((unsigned long long)sb << 32) | (unsigned)c;
    atomicMin(&keys[row], key);                  // tie -> lowest code
  }
  // ---- phase B: full rescans, sliced over the codebook
  __shared__ __align__(16) float xs[128];
  __shared__ unsigned long long red[4];
  const unsigned nitems = *fcount * 8;
  for (unsigned item = blockIdx.x; item < nitems; item += gridDim.x) {
    const int row = fulll[item >> 3];
    const int slice = (int)(item & 7u);
    if (tid < 128)                               // stage x row
      xs[tid] = enc[(((size_t)(row >> 10) * 128 + tid) << 10) + (row & 1023)];
    __syncthreads();
    float xn = 0.f;                              // serial order (R4-identical)
    for (int c = 0; c < 128; ++c) xn += xs[c] * xs[c];
    const int k0 = slice * 1024 + tid * 4;
    float S[4];
    #pragma unroll
    for (int j = 0; j < 4; ++j) S[j] = 0.f;
    for (int c4 = 0; c4 < 32; ++c4) {
      float4 xv = *(const float4*)(&xs[c4 * 4]);
      #pragma unroll
      for (int j = 0; j < 4; ++j) {
        float4 wv = *(const float4*)(w + (size_t)(k0 + j) * C_DIM + c4 * 4);
        S[j] = fmaf(xv.x, wv.x, S[j]);
        S[j] = fmaf(xv.y, wv.y, S[j]);
        S[j] = fmaf(xv.z, wv.z, S[j]);
        S[j] = fmaf(xv.w, wv.w, S[j]);
      }
    }
    unsigned long long best = ~0ull;
    #pragma unroll
    for (int j = 0; j < 4; ++j) {
      float d = (xn + wnorm[k0 + j]) - 2.0f * S[j];
      unsigned sb = __float_as_uint(d);
      sb = (sb >> 31) ? ~sb : (sb | 0x80000000u);
      unsigned long long key = ((unsigned long long)sb << 32) | (unsigned)(k0 + j);
      best = best < key ? best : key;
    }
    #pragma unroll
    for (int s = 1; s <= 32; s <<= 1) {          // 64-lane u64 butterfly
      unsigned long long ok = __shfl_xor(best, s);
      best = ok < best ? ok : best;
    }
    if (lane == 0) red[wave] = best;
    __syncthreads();
    if (tid == 0) {
      unsigned long long bk = red[0];
      #pragma unroll
      for (int wv = 1; wv < 4; ++wv) bk = red[wv] < bk ? red[wv] : bk;
      atomicMin(&keys[row], bk);
    }
    __syncthreads();                             // xs reused next item
  }
}

// ---------------- fused tail: resolve + counts + sums + q + out_ids --------
__global__ void scatter_qsum(const float* __restrict__ enc,
                             const float* __restrict__ w,
                             const int* __restrict__ ids,
                             const unsigned long long* __restrict__ keys,
                             float* __restrict__ sums,
                             float* __restrict__ counts,
                             float* __restrict__ outq,
                             float* __restrict__ out_ids) {
  int e = blockIdx.x * 256 + threadIdx.x;        // linear over enc [B,C,H,W]
  int c = (e >> 10) & 127;
  int b = e >> 17;
  int n = (b << 10) | (e & 1023);
  unsigned long long k = keys[n];
  int id = (k != ~0ull) ? (int)(unsigned)(k & 0xffffffffu) : ids[n];
  float x = enc[e];
  unsafeAtomicAdd(&sums[(size_t)id * C_DIM + c], x);
  if (c == 0) {
    unsafeAtomicAdd(&counts[id], 1.0f);          // once per row n
    out_ids[n] = (float)id;
  }
  float wq = w[(size_t)id * C_DIM + c];
  outq[e] = x + (wq - x);                        // reference rounding order
}

// ---------------- finalize: EMA weight -------------------------------------
__global__ void finalize_w(const float* __restrict__ w,
                           const float* __restrict__ sums,
                           const float* __restrict__ counts,
                           float* __restrict__ outw) {
  int i = blockIdx.x * 256 + threadIdx.x;
  int k = i >> 7;
  const float omd = (float)(1.0 - 0.99);
  float mean = sums[i] / (counts[k] + 1e-12f);
  outw[i] = 0.99f * w[i] + omd * mean;
}

// ---------------------------------------------------------------------------
extern "C" void kernel_launch(void* const* d_in, const int* in_sizes, int n_in,
                              void* d_out, int out_size, void* d_ws, size_t ws_size,
                              hipStream_t stream) {
  const float* enc = (const float*)d_in[0];      // [16,128,32,32]
  const float* w   = (const float*)d_in[1];      // [8192,128]
  float* out = (float*)d_out;
  float* out_ids = out;                          // 16384 (ids as float)
  float* out_q   = out + N_ROWS;                 // 2097152
  float* out_w   = out + N_ROWS + N_ROWS * C_DIM;// 1048576

  char* ws = (char*)d_ws;
  _Float16* Ap  = (_Float16*)(ws);                         //  0 .. 4194304
  _Float16* Bp  = (_Float16*)(ws + 4194304);               //  .. 6291456
  float* xnorm  = (float*)(ws + 6291456);                  //  .. 6356992
  float* wnorm  = (float*)(ws + 6356992);                  //  .. 6389760
  float* pd1    = (float*)(ws + 6389760);                  // 64*16384*4 = 4 MB
  float* pd2    = (float*)(ws + 10584064);                 // 4 MB
  unsigned* pc1 = (unsigned*)(ws + 14778368);              // 4 MB
  int* ids      = (int*)(ws + 18972672);
  int* fulll    = (int*)(ws + 19038208);
  unsigned* items = (unsigned*)(ws + 19103744);
  unsigned* wnmax  = (unsigned*)(ws + 20152320);           // ctrl 16 B
  unsigned* icount = (unsigned*)(ws + 20152324);
  unsigned* fcount = (unsigned*)(ws + 20152328);
  float* counts = (float*)(ws + 20152336);
  float* sums   = (float*)(ws + 20185104);
  unsigned long long* keys = (unsigned long long*)(ws + 24379408);
  (void)in_sizes; (void)n_in; (void)out_size; (void)ws_size;

  // zero ctrl+counts+sums, then 0xFF keys (keys sentinel = ~0ull)
  hipMemsetAsync(ws + 20152320, 0, 16 + 32768 + 4194304, stream);
  hipMemsetAsync(ws + 24379408, 0xFF, N_ROWS * 8, stream);

  prep<<<384, 256, 0, stream>>>(enc, w, Ap, Bp, xnorm, wnorm, wnmax);
  gemm_argmin<<<dim3(8, N_ROWS / 128), 256, 0, stream>>>(
      Ap, Bp, xnorm, wnorm, pd1, pc1, pd2);
  merge_classify<<<N_ROWS / 256, 256, 0, stream>>>(
      pd1, pc1, pd2, xnorm, wnmax, ids, items, icount, fulll, fcount);
  refine<<<2048, 256, 0, stream>>>(enc, w, wnorm, items, icount, fulll, fcount,
                                   keys);
  scatter_qsum<<<(N_ROWS * C_DIM) / 256, 256, 0, stream>>>(
      enc, w, ids, keys, sums, counts, out_q, out_ids);
  finalize_w<<<(K_CODES * C_DIM) / 256, 256, 0, stream>>>(w, sums, counts, out_w);
}

// Round 9
// 325.232 us; speedup vs baseline: 1.7722x; 1.3098x over previous
//
#include <hip/hip_runtime.h>
#include <stdint.h>
#include <stddef.h>

// ---------------------------------------------------------------------------
// VQ-VAE quantizer, MI355X.  dist(n,k) = ||x||^2 + ||w_k||^2 - 2 x.w_k.
// f16 GEMM (KD=128), fragment-linear A/B, no LDS/barriers in K-loop.
// Refine (R4-proven): per-row threshold T = d1~ + 2E over 64 col-groups of
// 128 codes; group top-1s within T are candidates; any group top-2 within T
// -> exact full rescan.  Exact compares via u64 atomicMin keys.
// R9: EMA stats via CSR gather (resolve -> scan -> fill -> gather) instead
// of 2M fp32 scatter-atomics (R8's 74 MB atomic write-back, 135 us).
// ---------------------------------------------------------------------------

#define N_ROWS   16384      // B*H*W = 16*32*32
#define K_CODES  8192
#define C_DIM    128

typedef _Float16 f16x8 __attribute__((ext_vector_type(8)));
typedef float    f32x4 __attribute__((ext_vector_type(4)));

// ---------------- fused prep: blocks [0,256) pack x (+fp32 xT), [256,384) w
// Ap layout: half Ap[rowtile R=n>>4][kchunk C=c>>5][lane][8]
//   lane = (n&15) + 16*((c&31)>>3), elem j = c&7   (MFMA A-operand order)
__global__ __launch_bounds__(256) void prep(const float* __restrict__ enc,
                                            const float* __restrict__ w,
                                            _Float16* __restrict__ Ap,
                                            _Float16* __restrict__ Bp,
                                            float* __restrict__ xT,
                                            float* __restrict__ xnorm,
                                            float* __restrict__ wnorm,
                                            unsigned* __restrict__ wnmax) {
  __shared__ float t[128][65];
  const int tid = threadIdx.x;
  if (blockIdx.x < 256) {                        // ---- x path
    const int b = blockIdx.x >> 4;
    const int hw0 = (blockIdx.x & 15) << 6;
    #pragma unroll
    for (int i = 0; i < 32; ++i) {
      int idx = i * 256 + tid;
      int c = idx >> 6, hwl = idx & 63;
      t[c][hwl] = enc[((size_t)(b * 128 + c) << 10) + hw0 + hwl];
    }
    __syncthreads();
    const int r = tid >> 2, sub = tid & 3;       // row-in-block, k-chunk
    const int n = (b << 10) + hw0 + r;
    const int R = n >> 4, m = n & 15;
    float s = 0.f;
    #pragma unroll
    for (int q = 0; q < 4; ++q) {
      f16x8 hv;
      float vv[8];
      #pragma unroll
      for (int e = 0; e < 8; ++e) {
        float v = t[sub * 32 + q * 8 + e][r];
        vv[e] = v;
        s += v * v;
        hv[e] = (_Float16)v;
      }
      *(f16x8*)(Ap + ((size_t)(R * 4 + sub) * 64 + (m + 16 * q)) * 8) = hv;
      *(float4*)(xT + (size_t)n * 128 + sub * 32 + q * 8) =
          (float4){vv[0], vv[1], vv[2], vv[3]};
      *(float4*)(xT + (size_t)n * 128 + sub * 32 + q * 8 + 4) =
          (float4){vv[4], vv[5], vv[6], vv[7]};
    }
    s += __shfl_xor(s, 1);
    s += __shfl_xor(s, 2);
    if (sub == 0) xnorm[n] = s;
  } else {                                       // ---- w path
    const int kk = (blockIdx.x - 256) * 64 + (tid >> 2), sub = tid & 3;
    const int R = kk >> 4, m = kk & 15;
    const float* base = w + (size_t)kk * C_DIM + sub * 32;
    float s = 0.f;
    #pragma unroll
    for (int q = 0; q < 4; ++q) {
      f16x8 hv;
      float4 va = *(const float4*)(base + q * 8);
      float4 vb = *(const float4*)(base + q * 8 + 4);
      float vv[8] = {va.x, va.y, va.z, va.w, vb.x, vb.y, vb.z, vb.w};
      #pragma unroll
      for (int e = 0; e < 8; ++e) { s += vv[e] * vv[e]; hv[e] = (_Float16)vv[e]; }
      *(f16x8*)(Bp + ((size_t)(R * 4 + sub) * 64 + (m + 16 * q)) * 8) = hv;
    }
    s += __shfl_xor(s, 1);
    s += __shfl_xor(s, 2);
    if (sub == 0) {
      wnorm[kk] = s;
      atomicMax(wnmax, __float_as_uint(s));      // s > 0 -> bit-monotone
    }
  }
}

// ---------------- main GEMM + per-(row,128col-group) top-2 -----------------
// Grid (8 colsplits, 128 rowblocks); block sweeps 8 groups of 128 cols.
// Wave tile 32 rows x 128 cols (2ti x 8tj MFMA f32_16x16x32_f16); hoisted
// A-fragments; fresh top-2 + one 16-lane butterfly per group.
__global__ __launch_bounds__(256) void gemm_argmin(
    const _Float16* __restrict__ Ap, const _Float16* __restrict__ Bp,
    const float* __restrict__ xnorm, const float* __restrict__ wnorm,
    float* __restrict__ pd1, unsigned* __restrict__ pc1,
    float* __restrict__ pd2)
{
  const int tid = threadIdx.x;
  const int lane = tid & 63, wave = tid >> 6;
  const int m = lane & 15, q = lane >> 4;
  const int cs = blockIdx.x;                     // col slice (1024 cols)
  const int row0 = blockIdx.y * 128;
  const int Tr = blockIdx.y * 8 + wave * 2;      // wave's 2 row-tiles

  f16x8 a0[4], a1[4];                            // it-invariant A fragments
  #pragma unroll
  for (int kc = 0; kc < 4; ++kc) {
    a0[kc] = *(const f16x8*)(Ap + (((size_t)Tr * 4 + kc) << 9) + (lane << 3));
    a1[kc] = *(const f16x8*)(Ap + (((size_t)(Tr + 1) * 4 + kc) << 9) + (lane << 3));
  }

  for (int it = 0; it < 8; ++it) {               // ascending col groups
    const int T0 = cs * 64 + it * 8;             // col-tile base
    const int g = cs * 8 + it;                   // group index [0,64)
    f32x4 acc[2][8];
    #pragma unroll
    for (int ti = 0; ti < 2; ++ti)
      #pragma unroll
      for (int tj = 0; tj < 8; ++tj) acc[ti][tj] = (f32x4){0.f, 0.f, 0.f, 0.f};
    #pragma unroll
    for (int kc = 0; kc < 4; ++kc) {
      #pragma unroll
      for (int tj = 0; tj < 8; ++tj) {
        f16x8 b = *(const f16x8*)(Bp + (((size_t)(T0 + tj) * 4 + kc) << 9) + (lane << 3));
        acc[0][tj] = __builtin_amdgcn_mfma_f32_16x16x32_f16(a0[kc], b, acc[0][tj], 0, 0, 0);
        acc[1][tj] = __builtin_amdgcn_mfma_f32_16x16x32_f16(a1[kc], b, acc[1][tj], 0, 0, 0);
      }
    }
    // fresh top-2 for this group; C/D layout col=lane&15, row=4q+r_
    float d1[8], d2[8]; unsigned c1[8];
    #pragma unroll
    for (int r = 0; r < 8; ++r) {
      d1[r] = __builtin_inff(); d2[r] = __builtin_inff(); c1[r] = 0;
    }
    #pragma unroll
    for (int tj = 0; tj < 8; ++tj) {             // ascending col; tie -> lower
      unsigned cc = (unsigned)((T0 + tj) * 16 + m);
      float wn = wnorm[cc];
      #pragma unroll
      for (int ti = 0; ti < 2; ++ti)
        #pragma unroll
        for (int r_ = 0; r_ < 4; ++r_) {
          int r = ti * 4 + r_;
          float dd = fmaf(-2.0f, acc[ti][tj][r_], wn);
          if (dd < d1[r]) { d2[r] = d1[r]; d1[r] = dd; c1[r] = cc; }
          else            { d2[r] = fminf(d2[r], dd); }
        }
    }
    // one 16-lane butterfly per row; lex (d,c) keeps first-min tie rule
    #pragma unroll
    for (int r = 0; r < 8; ++r) {
      float a1v = d1[r], a2v = d2[r]; unsigned ac = c1[r];
      #pragma unroll
      for (int s = 1; s <= 8; s <<= 1) {
        float    o1 = __shfl_xor(a1v, s), o2 = __shfl_xor(a2v, s);
        unsigned oc = (unsigned)__shfl_xor((int)ac, s);
        float n2 = fminf(fminf(a2v, o2), fmaxf(a1v, o1));
        if (o1 < a1v || (o1 == a1v && oc < ac)) { a1v = o1; ac = oc; }
        a2v = n2;
      }
      if (m == 0) {
        int row = row0 + wave * 32 + (r >> 2) * 16 + 4 * q + (r & 3);
        float xn = xnorm[row];
        size_t pi = (size_t)g * N_ROWS + row;
        pd1[pi] = xn + a1v; pc1[pi] = ac; pd2[pi] = xn + a2v;
      }
    }
  }
}

// ---------------- classify: threshold-collect over 64 groups ---------------
__global__ void merge_classify(const float* __restrict__ pd1,
                               const unsigned* __restrict__ pc1,
                               const float* __restrict__ pd2,
                               const float* __restrict__ xnorm,
                               const unsigned* __restrict__ wnmax,
                               int* __restrict__ ids,
                               unsigned* __restrict__ items,
                               unsigned* __restrict__ icount,
                               int* __restrict__ fulll,
                               unsigned* __restrict__ fcount) {
  int row = blockIdx.x * 256 + threadIdx.x;
  float da = __builtin_inff(), db = __builtin_inff(),
        dc = __builtin_inff(), dd = __builtin_inff();
  unsigned ca = 0, cb_ = 0, cc = 0, cd = 0;
  for (int cb = 0; cb < 64; cb += 4) {
    size_t i0 = (size_t)cb * N_ROWS + row;
    float va = pd1[i0], vb = pd1[i0 + (size_t)N_ROWS],
          vc = pd1[i0 + 2 * (size_t)N_ROWS], vd = pd1[i0 + 3 * (size_t)N_ROWS];
    unsigned ka = pc1[i0], kb = pc1[i0 + (size_t)N_ROWS],
             kc = pc1[i0 + 2 * (size_t)N_ROWS], kd = pc1[i0 + 3 * (size_t)N_ROWS];
    if (va < da || (va == da && ka < ca)) { da = va; ca = ka; }
    if (vb < db || (vb == db && kb < cb_)) { db = vb; cb_ = kb; }
    if (vc < dc || (vc == dc && kc < cc)) { dc = vc; cc = kc; }
    if (vd < dd || (vd == dd && kd < cd)) { dd = vd; cd = kd; }
  }
  float d1 = da; unsigned c1 = ca;
  if (db < d1 || (db == d1 && cb_ < c1)) { d1 = db; c1 = cb_; }
  if (dc < d1 || (dc == d1 && cc < c1)) { d1 = dc; c1 = cc; }
  if (dd < d1 || (dd == d1 && cd < c1)) { d1 = dd; c1 = cd; }

  float wm = __uint_as_float(*wnmax);
  float twoE = 2.0f * (0.0029297f * sqrtf(xnorm[row] * wm) + 2e-4f);
  float T = d1 + twoE;
  bool full = false;
  int nc = 0;
  unsigned cands[6];
  #pragma unroll 4
  for (int cb = 0; cb < 64; ++cb) {
    size_t i = (size_t)cb * N_ROWS + row;
    if (pd2[i] <= T) { full = true; }
    else if (pd1[i] <= T) {
      if (nc < 6) cands[nc++] = pc1[i];
      else full = true;
    }
  }
  ids[row] = (int)c1;                            // exact if nc==1 && !full
  if (full) {
    unsigned fi = atomicAdd(fcount, 1u);
    fulll[fi] = row;
  } else if (nc >= 2) {
    unsigned base = atomicAdd(icount, (unsigned)nc);
    for (int i = 0; i < nc; ++i)
      items[base + i] = ((unsigned)row << 13) | cands[i];
  }
}

// ---------------- fused exact refine: items (phase A) + full (phase B) -----
__global__ __launch_bounds__(256) void refine(
    const float* __restrict__ enc, const float* __restrict__ w,
    const float* __restrict__ wnorm,
    const unsigned* __restrict__ items, const unsigned* __restrict__ icount,
    const int* __restrict__ fulll, const unsigned* __restrict__ fcount,
    unsigned long long* __restrict__ keys) {
  const int tid = threadIdx.x;
  const int lane = tid & 63, wave = tid >> 6;
  // ---- phase A: candidate items
  const unsigned ic = *icount;
  for (unsigned i = blockIdx.x * 256 + tid; i < ic; i += gridDim.x * 256) {
    unsigned it = items[i];
    int row = (int)(it >> 13), c = (int)(it & 8191u);
    int b = row >> 10, hw = row & 1023;
    const float* xb = enc + ((size_t)b << 17) + hw;
    const float* wk = w + (size_t)c * C_DIM;
    float xn = 0.f, s = 0.f;
    for (int cc = 0; cc < C_DIM; ++cc) {
      float x = xb[(size_t)cc << 10];
      xn += x * x;
      s = fmaf(x, wk[cc], s);
    }
    float d = (xn + wnorm[c]) - 2.0f * s;
    unsigned sb = __float_as_uint(d);
    sb = (sb >> 31) ? ~sb : (sb | 0x80000000u);  // sortable float bits
    unsigned long long key = ((unsigned long long)sb << 32) | (unsigned)c;
    atomicMin(&keys[row], key);                  // tie -> lowest code
  }
  // ---- phase B: full rescans, sliced over the codebook
  __shared__ __align__(16) float xs[128];
  __shared__ unsigned long long red[4];
  const unsigned nitems = *fcount * 8;
  for (unsigned item = blockIdx.x; item < nitems; item += gridDim.x) {
    const int row = fulll[item >> 3];
    const int slice = (int)(item & 7u);
    if (tid < 128)                               // stage x row
      xs[tid] = enc[(((size_t)(row >> 10) * 128 + tid) << 10) + (row & 1023)];
    __syncthreads();
    float xn = 0.f;                              // serial order (R4-identical)
    for (int c = 0; c < 128; ++c) xn += xs[c] * xs[c];
    const int k0 = slice * 1024 + tid * 4;
    float S[4];
    #pragma unroll
    for (int j = 0; j < 4; ++j) S[j] = 0.f;
    for (int c4 = 0; c4 < 32; ++c4) {
      float4 xv = *(const float4*)(&xs[c4 * 4]);
      #pragma unroll
      for (int j = 0; j < 4; ++j) {
        float4 wv = *(const float4*)(w + (size_t)(k0 + j) * C_DIM + c4 * 4);
        S[j] = fmaf(xv.x, wv.x, S[j]);
        S[j] = fmaf(xv.y, wv.y, S[j]);
        S[j] = fmaf(xv.z, wv.z, S[j]);
        S[j] = fmaf(xv.w, wv.w, S[j]);
      }
    }
    unsigned long long best = ~0ull;
    #pragma unroll
    for (int j = 0; j < 4; ++j) {
      float d = (xn + wnorm[k0 + j]) - 2.0f * S[j];
      unsigned sb = __float_as_uint(d);
      sb = (sb >> 31) ? ~sb : (sb | 0x80000000u);
      unsigned long long key = ((unsigned long long)sb << 32) | (unsigned)(k0 + j);
      best = best < key ? best : key;
    }
    #pragma unroll
    for (int s = 1; s <= 32; s <<= 1) {          // 64-lane u64 butterfly
      unsigned long long ok = __shfl_xor(best, s);
      best = ok < best ? ok : best;
    }
    if (lane == 0) red[wave] = best;
    __syncthreads();
    if (tid == 0) {
      unsigned long long bk = red[0];
      #pragma unroll
      for (int wv = 1; wv < 4; ++wv) bk = red[wv] < bk ? red[wv] : bk;
      atomicMin(&keys[row], bk);
    }
    __syncthreads();                             // xs reused next item
  }
}

// ---------------- resolve final ids + int counts + out_ids -----------------
__global__ void resolve_ids(const unsigned long long* __restrict__ keys,
                            int* __restrict__ ids, unsigned* __restrict__ cnt,
                            float* __restrict__ out_ids) {
  int row = blockIdx.x * 256 + threadIdx.x;
  unsigned long long k = keys[row];
  int id = (k != ~0ull) ? (int)(unsigned)(k & 0xffffffffu) : ids[row];
  ids[row] = id;
  out_ids[row] = (float)id;
  atomicAdd(&cnt[id], 1u);
}

// ---------------- exclusive scan of counts -> offs + cursor (1 block) ------
__global__ __launch_bounds__(256) void scan_offsets(
    const unsigned* __restrict__ cnt,
    unsigned* __restrict__ offs, unsigned* __restrict__ cursor) {
  __shared__ unsigned tot[256];
  const int tid = threadIdx.x;
  unsigned local[32], run = 0;
  #pragma unroll
  for (int i = 0; i < 32; ++i) { local[i] = run; run += cnt[tid * 32 + i]; }
  tot[tid] = run;
  __syncthreads();
  for (int st = 1; st < 256; st <<= 1) {
    unsigned v = (tid >= st) ? tot[tid - st] : 0u;
    __syncthreads();
    tot[tid] += v;
    __syncthreads();
  }
  unsigned excl = (tid == 0) ? 0u : tot[tid - 1];
  #pragma unroll
  for (int i = 0; i < 32; ++i) {
    unsigned o = excl + local[i];
    offs[tid * 32 + i] = o;
    cursor[tid * 32 + i] = o;
  }
}

// ---------------- fill CSR row list ----------------------------------------
__global__ void fill_rowlist(const int* __restrict__ ids,
                             unsigned* __restrict__ cursor,
                             int* __restrict__ rowlist) {
  int row = blockIdx.x * 256 + threadIdx.x;
  unsigned slot = atomicAdd(&cursor[ids[row]], 1u);
  rowlist[slot] = row;
}

// ---------------- straight-through q (pure, no atomics) --------------------
__global__ void write_q(const float* __restrict__ enc,
                        const float* __restrict__ w,
                        const int* __restrict__ ids,
                        float* __restrict__ outq) {
  int e = blockIdx.x * 256 + threadIdx.x;        // linear over enc [B,C,H,W]
  int c = (e >> 10) & 127;
  int b = e >> 17;
  int n = (b << 10) | (e & 1023);
  float x = enc[e];
  float wq = w[(size_t)ids[n] * C_DIM + c];
  outq[e] = x + (wq - x);                        // reference rounding order
}

// ---------------- finalize: EMA weight via CSR gather (wave per code) ------
__global__ __launch_bounds__(256) void finalize_w(
    const float* __restrict__ w, const float* __restrict__ xT,
    const unsigned* __restrict__ cnt, const unsigned* __restrict__ offs,
    const int* __restrict__ rowlist, float* __restrict__ outw) {
  const int tid = threadIdx.x;
  const int lane = tid & 63, wave = tid >> 6;
  const int k = blockIdx.x * 4 + wave;
  const unsigned n0 = offs[k], nk = cnt[k];
  float S0 = 0.f, S1 = 0.f;
  for (unsigned i = 0; i < nk; ++i) {
    int row = rowlist[n0 + i];
    S0 += xT[(size_t)row * 128 + lane];
    S1 += xT[(size_t)row * 128 + lane + 64];
  }
  const float omd = (float)(1.0 - 0.99);
  float cf = (float)nk + 1e-12f;
  outw[(size_t)k * 128 + lane]      = 0.99f * w[(size_t)k * 128 + lane]      + omd * (S0 / cf);
  outw[(size_t)k * 128 + lane + 64] = 0.99f * w[(size_t)k * 128 + lane + 64] + omd * (S1 / cf);
}

// ---------------------------------------------------------------------------
extern "C" void kernel_launch(void* const* d_in, const int* in_sizes, int n_in,
                              void* d_out, int out_size, void* d_ws, size_t ws_size,
                              hipStream_t stream) {
  const float* enc = (const float*)d_in[0];      // [16,128,32,32]
  const float* w   = (const float*)d_in[1];      // [8192,128]
  float* out = (float*)d_out;
  float* out_ids = out;                          // 16384 (ids as float)
  float* out_q   = out + N_ROWS;                 // 2097152
  float* out_w   = out + N_ROWS + N_ROWS * C_DIM;// 1048576

  char* ws = (char*)d_ws;
  _Float16* Ap  = (_Float16*)(ws);                         //  0 .. 4194304
  _Float16* Bp  = (_Float16*)(ws + 4194304);               //  .. 6291456
  float* xnorm  = (float*)(ws + 6291456);                  //  .. 6356992
  float* wnorm  = (float*)(ws + 6356992);                  //  .. 6389760
  float* pd1    = (float*)(ws + 6389760);                  // 4 MB
  float* pd2    = (float*)(ws + 10584064);                 // 4 MB
  unsigned* pc1 = (unsigned*)(ws + 14778368);              // 4 MB
  int* ids      = (int*)(ws + 18972672);                   // 64 KB
  int* fulll    = (int*)(ws + 19038208);                   // 64 KB
  unsigned* items = (unsigned*)(ws + 19103744);            // 1 MB
  unsigned* wnmax  = (unsigned*)(ws + 20152320);           // ctrl 16 B
  unsigned* icount = (unsigned*)(ws + 20152324);
  unsigned* fcount = (unsigned*)(ws + 20152328);
  unsigned* cnt    = (unsigned*)(ws + 20152336);           // 32 KB (int counts)
  unsigned* offs   = (unsigned*)(ws + 20185104);           // 32 KB
  unsigned* cursor = (unsigned*)(ws + 20217872);           // 32 KB
  unsigned long long* keys = (unsigned long long*)(ws + 20250640); // 128 KB
  int* rowlist  = (int*)(ws + 20381712);                   // 64 KB
  float* xT     = (float*)(ws + 20447248);                 // 8 MB .. 28835856
  (void)in_sizes; (void)n_in; (void)out_size; (void)ws_size;

  // zero ctrl + cnt (contiguous), 0xFF keys (sentinel ~0ull)
  hipMemsetAsync(ws + 20152320, 0, 16 + 32768, stream);
  hipMemsetAsync(ws + 20250640, 0xFF, N_ROWS * 8, stream);

  prep<<<384, 256, 0, stream>>>(enc, w, Ap, Bp, xT, xnorm, wnorm, wnmax);
  gemm_argmin<<<dim3(8, N_ROWS / 128), 256, 0, stream>>>(
      Ap, Bp, xnorm, wnorm, pd1, pc1, pd2);
  merge_classify<<<N_ROWS / 256, 256, 0, stream>>>(
      pd1, pc1, pd2, xnorm, wnmax, ids, items, icount, fulll, fcount);
  refine<<<2048, 256, 0, stream>>>(enc, w, wnorm, items, icount, fulll, fcount,
                                   keys);
  resolve_ids<<<N_ROWS / 256, 256, 0, stream>>>(keys, ids, cnt, out_ids);
  scan_offsets<<<1, 256, 0, stream>>>(cnt, offs, cursor);
  fill_rowlist<<<N_ROWS / 256, 256, 0, stream>>>(ids, cursor, rowlist);
  write_q<<<(N_ROWS * C_DIM) / 256, 256, 0, stream>>>(enc, w, ids, out_q);
  finalize_w<<<K_CODES / 4, 256, 0, stream>>>(w, xT, cnt, offs, rowlist, out_w);
}

// Round 10
// 302.512 us; speedup vs baseline: 1.9053x; 1.0751x over previous
//
#include <hip/hip_runtime.h>
#include <stdint.h>
#include <stddef.h>

// ---------------------------------------------------------------------------
// VQ-VAE quantizer, MI355X.  dist(n,k) = ||x||^2 + ||w_k||^2 - 2 x.w_k.
// f16 GEMM (KD=128), fragment-linear A/B, no LDS/barriers in K-loop.
// Refine (R4-proven): per-row threshold T = d1~ + 2E over 64 col-groups of
// 128 codes; group top-1s within T are candidates; any group top-2 within T
// -> exact full rescan.  Exact compares via u64 atomicMin keys.
// R10: gemm operands SWAPPED (codes = M dim): D col = x-row, D row = code,
// so each lane owns one row x 32 codes per group -> cross-lane top-2 reduce
// shrinks from 4-stage/16-lane x 8 reg-rows to one 2-stage/4-lane reduce.
// finalize_w sums segments in ascending row order (reference-identical).
// ---------------------------------------------------------------------------

#define N_ROWS   16384      // B*H*W = 16*32*32
#define K_CODES  8192
#define C_DIM    128

typedef _Float16 f16x8 __attribute__((ext_vector_type(8)));
typedef float    f32x4 __attribute__((ext_vector_type(4)));

// ---------------- fused prep: blocks [0,256) pack x (+fp32 xT), [256,384) w
// Fragment-linear layout: half P[tile16 T=i>>4][kchunk C=c>>5][lane][8]
//   lane = (i&15) + 16*((c&31)>>3), elem j = c&7  (valid as MFMA A or B frag)
__global__ __launch_bounds__(256) void prep(const float* __restrict__ enc,
                                            const float* __restrict__ w,
                                            _Float16* __restrict__ Ap,
                                            _Float16* __restrict__ Bp,
                                            float* __restrict__ xT,
                                            float* __restrict__ xnorm,
                                            float* __restrict__ wnorm,
                                            unsigned* __restrict__ wnmax) {
  __shared__ float t[128][65];
  const int tid = threadIdx.x;
  if (blockIdx.x < 256) {                        // ---- x path
    const int b = blockIdx.x >> 4;
    const int hw0 = (blockIdx.x & 15) << 6;
    #pragma unroll
    for (int i = 0; i < 32; ++i) {
      int idx = i * 256 + tid;
      int c = idx >> 6, hwl = idx & 63;
      t[c][hwl] = enc[((size_t)(b * 128 + c) << 10) + hw0 + hwl];
    }
    __syncthreads();
    const int r = tid >> 2, sub = tid & 3;       // row-in-block, k-chunk
    const int n = (b << 10) + hw0 + r;
    const int R = n >> 4, m = n & 15;
    float s = 0.f;
    #pragma unroll
    for (int q = 0; q < 4; ++q) {
      f16x8 hv;
      float vv[8];
      #pragma unroll
      for (int e = 0; e < 8; ++e) {
        float v = t[sub * 32 + q * 8 + e][r];
        vv[e] = v;
        s += v * v;
        hv[e] = (_Float16)v;
      }
      *(f16x8*)(Ap + ((size_t)(R * 4 + sub) * 64 + (m + 16 * q)) * 8) = hv;
      *(float4*)(xT + (size_t)n * 128 + sub * 32 + q * 8) =
          (float4){vv[0], vv[1], vv[2], vv[3]};
      *(float4*)(xT + (size_t)n * 128 + sub * 32 + q * 8 + 4) =
          (float4){vv[4], vv[5], vv[6], vv[7]};
    }
    s += __shfl_xor(s, 1);
    s += __shfl_xor(s, 2);
    if (sub == 0) xnorm[n] = s;
  } else {                                       // ---- w path
    const int kk = (blockIdx.x - 256) * 64 + (tid >> 2), sub = tid & 3;
    const int R = kk >> 4, m = kk & 15;
    const float* base = w + (size_t)kk * C_DIM + sub * 32;
    float s = 0.f;
    #pragma unroll
    for (int q = 0; q < 4; ++q) {
      f16x8 hv;
      float4 va = *(const float4*)(base + q * 8);
      float4 vb = *(const float4*)(base + q * 8 + 4);
      float vv[8] = {va.x, va.y, va.z, va.w, vb.x, vb.y, vb.z, vb.w};
      #pragma unroll
      for (int e = 0; e < 8; ++e) { s += vv[e] * vv[e]; hv[e] = (_Float16)vv[e]; }
      *(f16x8*)(Bp + ((size_t)(R * 4 + sub) * 64 + (m + 16 * q)) * 8) = hv;
    }
    s += __shfl_xor(s, 1);
    s += __shfl_xor(s, 2);
    if (sub == 0) {
      wnorm[kk] = s;
      atomicMax(wnmax, __float_as_uint(s));      // s > 0 -> bit-monotone
    }
  }
}

// ---------------- main GEMM + per-(row,128col-group) top-2 -----------------
// Grid (8 colsplits, 128 rowblocks), 512 thr = 8 waves.  Wave tile: 16 rows
// (one row-tile, B operand) x 128 codes (8 tiles, A operand) per group.
// mfma(a=codes, b=rows): D col = lane&15 = x-row, D row = 4q+r = code.
// Lane owns 1 row x 32 codes/group; top-2 scan in-lane, then 2-stage
// shfl_xor(16,32) reduce over q.  Scan key = wn - 2S; xn added at write.
__global__ __launch_bounds__(512) void gemm_argmin(
    const _Float16* __restrict__ Ap, const _Float16* __restrict__ Bp,
    const float* __restrict__ xnorm, const float* __restrict__ wnorm,
    float* __restrict__ pd1, unsigned* __restrict__ pc1,
    float* __restrict__ pd2)
{
  const int tid = threadIdx.x;
  const int lane = tid & 63, wave = tid >> 6;    // 8 waves
  const int m = lane & 15, q = lane >> 4;
  const int cs = blockIdx.x;                     // col slice (1024 codes)
  const int row0 = blockIdx.y * 128;
  const int Tr = blockIdx.y * 8 + wave;          // wave's 16-row tile

  f16x8 bx[4];                                   // x-row fragments (invariant)
  #pragma unroll
  for (int kc = 0; kc < 4; ++kc)
    bx[kc] = *(const f16x8*)(Ap + (((size_t)Tr * 4 + kc) << 9) + (lane << 3));
  const float xn = xnorm[row0 + wave * 16 + m];  // this lane's x-row

  for (int it = 0; it < 8; ++it) {               // ascending col groups
    const int T0 = cs * 64 + it * 8;             // code-tile base
    const int g = cs * 8 + it;                   // group index [0,64)
    f32x4 acc[8];
    #pragma unroll
    for (int tj = 0; tj < 8; ++tj) acc[tj] = (f32x4){0.f, 0.f, 0.f, 0.f};
    #pragma unroll
    for (int kc = 0; kc < 4; ++kc) {
      #pragma unroll
      for (int tj = 0; tj < 8; ++tj) {
        f16x8 a = *(const f16x8*)(Bp + (((size_t)(T0 + tj) * 4 + kc) << 9) + (lane << 3));
        acc[tj] = __builtin_amdgcn_mfma_f32_16x16x32_f16(a, bx[kc], acc[tj], 0, 0, 0);
      }
    }
    // in-lane top-2 over 32 codes (ascending code; strict < -> lowest wins)
    float d1 = __builtin_inff(), d2 = __builtin_inff();
    unsigned c1 = 0;
    #pragma unroll
    for (int tj = 0; tj < 8; ++tj) {
      const int cb = (T0 + tj) * 16 + 4 * q;
      float4 wnq = *(const float4*)(wnorm + cb);
      #pragma unroll
      for (int r = 0; r < 4; ++r) {
        float wv = (r == 0) ? wnq.x : (r == 1) ? wnq.y : (r == 2) ? wnq.z : wnq.w;
        float dd = fmaf(-2.0f, acc[tj][r], wv);
        unsigned cc = (unsigned)(cb + r);
        if (dd < d1) { d2 = d1; d1 = dd; c1 = cc; }
        else         { d2 = fminf(d2, dd); }
      }
    }
    // reduce across q (lanes differing in bits 4,5); lex (d,c) tie rule
    #pragma unroll
    for (int s = 16; s <= 32; s <<= 1) {
      float    od1 = __shfl_xor(d1, s), od2 = __shfl_xor(d2, s);
      unsigned oc1 = (unsigned)__shfl_xor((int)c1, s);
      float nd2 = fminf(fminf(d2, od2), fmaxf(d1, od1));
      if (od1 < d1 || (od1 == d1 && oc1 < c1)) { d1 = od1; c1 = oc1; }
      d2 = nd2;
    }
    if (q == 0) {
      int row = row0 + wave * 16 + m;
      size_t pi = (size_t)g * N_ROWS + row;
      pd1[pi] = xn + d1; pc1[pi] = c1; pd2[pi] = xn + d2;
    }
  }
}

// ---------------- classify: threshold-collect over 64 groups ---------------
__global__ void merge_classify(const float* __restrict__ pd1,
                               const unsigned* __restrict__ pc1,
                               const float* __restrict__ pd2,
                               const float* __restrict__ xnorm,
                               const unsigned* __restrict__ wnmax,
                               int* __restrict__ ids,
                               unsigned* __restrict__ items,
                               unsigned* __restrict__ icount,
                               int* __restrict__ fulll,
                               unsigned* __restrict__ fcount) {
  int row = blockIdx.x * 256 + threadIdx.x;
  float da = __builtin_inff(), db = __builtin_inff(),
        dc = __builtin_inff(), dd = __builtin_inff();
  unsigned ca = 0, cb_ = 0, cc = 0, cd = 0;
  for (int cb = 0; cb < 64; cb += 4) {
    size_t i0 = (size_t)cb * N_ROWS + row;
    float va = pd1[i0], vb = pd1[i0 + (size_t)N_ROWS],
          vc = pd1[i0 + 2 * (size_t)N_ROWS], vd = pd1[i0 + 3 * (size_t)N_ROWS];
    unsigned ka = pc1[i0], kb = pc1[i0 + (size_t)N_ROWS],
             kc = pc1[i0 + 2 * (size_t)N_ROWS], kd = pc1[i0 + 3 * (size_t)N_ROWS];
    if (va < da || (va == da && ka < ca)) { da = va; ca = ka; }
    if (vb < db || (vb == db && kb < cb_)) { db = vb; cb_ = kb; }
    if (vc < dc || (vc == dc && kc < cc)) { dc = vc; cc = kc; }
    if (vd < dd || (vd == dd && kd < cd)) { dd = vd; cd = kd; }
  }
  float d1 = da; unsigned c1 = ca;
  if (db < d1 || (db == d1 && cb_ < c1)) { d1 = db; c1 = cb_; }
  if (dc < d1 || (dc == d1 && cc < c1)) { d1 = dc; c1 = cc; }
  if (dd < d1 || (dd == d1 && cd < c1)) { d1 = dd; c1 = cd; }

  float wm = __uint_as_float(*wnmax);
  float twoE = 2.0f * (0.0029297f * sqrtf(xnorm[row] * wm) + 2e-4f);
  float T = d1 + twoE;
  bool full = false;
  int nc = 0;
  unsigned cands[6];
  #pragma unroll 4
  for (int cb = 0; cb < 64; ++cb) {
    size_t i = (size_t)cb * N_ROWS + row;
    if (pd2[i] <= T) { full = true; }
    else if (pd1[i] <= T) {
      if (nc < 6) cands[nc++] = pc1[i];
      else full = true;
    }
  }
  ids[row] = (int)c1;                            // exact if nc==1 && !full
  if (full) {
    unsigned fi = atomicAdd(fcount, 1u);
    fulll[fi] = row;
  } else if (nc >= 2) {
    unsigned base = atomicAdd(icount, (unsigned)nc);
    for (int i = 0; i < nc; ++i)
      items[base + i] = ((unsigned)row << 13) | cands[i];
  }
}

// ---------------- fused exact refine: items (phase A) + full (phase B) -----
__global__ __launch_bounds__(256) void refine(
    const float* __restrict__ enc, const float* __restrict__ w,
    const float* __restrict__ wnorm,
    const unsigned* __restrict__ items, const unsigned* __restrict__ icount,
    const int* __restrict__ fulll, const unsigned* __restrict__ fcount,
    unsigned long long* __restrict__ keys) {
  const int tid = threadIdx.x;
  const int lane = tid & 63, wave = tid >> 6;
  // ---- phase A: candidate items
  const unsigned ic = *icount;
  for (unsigned i = blockIdx.x * 256 + tid; i < ic; i += gridDim.x * 256) {
    unsigned it = items[i];
    int row = (int)(it >> 13), c = (int)(it & 8191u);
    int b = row >> 10, hw = row & 1023;
    const float* xb = enc + ((size_t)b << 17) + hw;
    const float* wk = w + (size_t)c * C_DIM;
    float xn = 0.f, s = 0.f;
    for (int cc = 0; cc < C_DIM; ++cc) {
      float x = xb[(size_t)cc << 10];
      xn += x * x;
      s = fmaf(x, wk[cc], s);
    }
    float d = (xn + wnorm[c]) - 2.0f * s;
    unsigned sb = __float_as_uint(d);
    sb = (sb >> 31) ? ~sb : (sb | 0x80000000u);  // sortable float bits
    unsigned long long key = ((unsigned long long)sb << 32) | (unsigned)c;
    atomicMin(&keys[row], key);                  // tie -> lowest code
  }
  // ---- phase B: full rescans, sliced over the codebook
  __shared__ __align__(16) float xs[128];
  __shared__ unsigned long long red[4];
  const unsigned nitems = *fcount * 8;
  for (unsigned item = blockIdx.x; item < nitems; item += gridDim.x) {
    const int row = fulll[item >> 3];
    const int slice = (int)(item & 7u);
    if (tid < 128)                               // stage x row
      xs[tid] = enc[(((size_t)(row >> 10) * 128 + tid) << 10) + (row & 1023)];
    __syncthreads();
    float xn = 0.f;                              // serial order (R4-identical)
    for (int c = 0; c < 128; ++c) xn += xs[c] * xs[c];
    const int k0 = slice * 1024 + tid * 4;
    float S[4];
    #pragma unroll
    for (int j = 0; j < 4; ++j) S[j] = 0.f;
    for (int c4 = 0; c4 < 32; ++c4) {
      float4 xv = *(const float4*)(&xs[c4 * 4]);
      #pragma unroll
      for (int j = 0; j < 4; ++j) {
        float4 wv = *(const float4*)(w + (size_t)(k0 + j) * C_DIM + c4 * 4);
        S[j] = fmaf(xv.x, wv.x, S[j]);
        S[j] = fmaf(xv.y, wv.y, S[j]);
        S[j] = fmaf(xv.z, wv.z, S[j]);
        S[j] = fmaf(xv.w, wv.w, S[j]);
      }
    }
    unsigned long long best = ~0ull;
    #pragma unroll
    for (int j = 0; j < 4; ++j) {
      float d = (xn + wnorm[k0 + j]) - 2.0f * S[j];
      unsigned sb = __float_as_uint(d);
      sb = (sb >> 31) ? ~sb : (sb | 0x80000000u);
      unsigned long long key = ((unsigned long long)sb << 32) | (unsigned)(k0 + j);
      best = best < key ? best : key;
    }
    #pragma unroll
    for (int s = 1; s <= 32; s <<= 1) {          // 64-lane u64 butterfly
      unsigned long long ok = __shfl_xor(best, s);
      best = ok < best ? ok : best;
    }
    if (lane == 0) red[wave] = best;
    __syncthreads();
    if (tid == 0) {
      unsigned long long bk = red[0];
      #pragma unroll
      for (int wv = 1; wv < 4; ++wv) bk = red[wv] < bk ? red[wv] : bk;
      atomicMin(&keys[row], bk);
    }
    __syncthreads();                             // xs reused next item
  }
}

// ---------------- resolve final ids + int counts + out_ids -----------------
__global__ void resolve_ids(const unsigned long long* __restrict__ keys,
                            int* __restrict__ ids, unsigned* __restrict__ cnt,
                            float* __restrict__ out_ids) {
  int row = blockIdx.x * 256 + threadIdx.x;
  unsigned long long k = keys[row];
  int id = (k != ~0ull) ? (int)(unsigned)(k & 0xffffffffu) : ids[row];
  ids[row] = id;
  out_ids[row] = (float)id;
  atomicAdd(&cnt[id], 1u);
}

// ---------------- exclusive scan of counts -> offs + cursor (1 block) ------
__global__ __launch_bounds__(256) void scan_offsets(
    const unsigned* __restrict__ cnt,
    unsigned* __restrict__ offs, unsigned* __restrict__ cursor) {
  __shared__ unsigned tot[256];
  const int tid = threadIdx.x;
  unsigned local[32], run = 0;
  #pragma unroll
  for (int i = 0; i < 32; ++i) { local[i] = run; run += cnt[tid * 32 + i]; }
  tot[tid] = run;
  __syncthreads();
  for (int st = 1; st < 256; st <<= 1) {
    unsigned v = (tid >= st) ? tot[tid - st] : 0u;
    __syncthreads();
    tot[tid] += v;
    __syncthreads();
  }
  unsigned excl = (tid == 0) ? 0u : tot[tid - 1];
  #pragma unroll
  for (int i = 0; i < 32; ++i) {
    unsigned o = excl + local[i];
    offs[tid * 32 + i] = o;
    cursor[tid * 32 + i] = o;
  }
}

// ---------------- fill CSR row list ----------------------------------------
__global__ void fill_rowlist(const int* __restrict__ ids,
                             unsigned* __restrict__ cursor,
                             int* __restrict__ rowlist) {
  int row = blockIdx.x * 256 + threadIdx.x;
  unsigned slot = atomicAdd(&cursor[ids[row]], 1u);
  rowlist[slot] = row;
}

// ---------------- straight-through q (pure, no atomics) --------------------
__global__ void write_q(const float* __restrict__ enc,
                        const float* __restrict__ w,
                        const int* __restrict__ ids,
                        float* __restrict__ outq) {
  int e = blockIdx.x * 256 + threadIdx.x;        // linear over enc [B,C,H,W]
  int c = (e >> 10) & 127;
  int b = e >> 17;
  int n = (b << 10) | (e & 1023);
  float x = enc[e];
  float wq = w[(size_t)ids[n] * C_DIM + c];
  outq[e] = x + (wq - x);                        // reference rounding order
}

// ---------------- finalize: EMA weight via CSR gather (wave per code) ------
// Segments sorted ascending before summing -> sum order matches the
// reference segment_sum (row-sequential scatter-add) bit-for-bit.
__global__ __launch_bounds__(256) void finalize_w(
    const float* __restrict__ w, const float* __restrict__ xT,
    const unsigned* __restrict__ cnt, const unsigned* __restrict__ offs,
    const int* __restrict__ rowlist, float* __restrict__ outw) {
  __shared__ int seg[4][128];
  const int tid = threadIdx.x;
  const int lane = tid & 63, wave = tid >> 6;
  const int k = blockIdx.x * 4 + wave;
  const unsigned n0 = offs[k], nk = cnt[k];
  const bool sortable = (nk <= 128u);
  if (sortable)
    for (unsigned i = lane; i < nk; i += 64) seg[wave][i] = rowlist[n0 + i];
  __syncthreads();
  if (sortable && lane == 0) {                   // tiny insertion sort
    for (int i = 1; i < (int)nk; ++i) {
      int v = seg[wave][i], j = i - 1;
      while (j >= 0 && seg[wave][j] > v) { seg[wave][j + 1] = seg[wave][j]; --j; }
      seg[wave][j + 1] = v;
    }
  }
  __syncthreads();
  float S0 = 0.f, S1 = 0.f;
  for (unsigned i = 0; i < nk; ++i) {
    int row = sortable ? seg[wave][i] : rowlist[n0 + i];
    S0 += xT[(size_t)row * 128 + lane];
    S1 += xT[(size_t)row * 128 + lane + 64];
  }
  const float omd = (float)(1.0 - 0.99);
  float cf = (float)nk + 1e-12f;
  outw[(size_t)k * 128 + lane]      = 0.99f * w[(size_t)k * 128 + lane]      + omd * (S0 / cf);
  outw[(size_t)k * 128 + lane + 64] = 0.99f * w[(size_t)k * 128 + lane + 64] + omd * (S1 / cf);
}

// ---------------------------------------------------------------------------
extern "C" void kernel_launch(void* const* d_in, const int* in_sizes, int n_in,
                              void* d_out, int out_size, void* d_ws, size_t ws_size,
                              hipStream_t stream) {
  const float* enc = (const float*)d_in[0];      // [16,128,32,32]
  const float* w   = (const float*)d_in[1];      // [8192,128]
  float* out = (float*)d_out;
  float* out_ids = out;                          // 16384 (ids as float)
  float* out_q   = out + N_ROWS;                 // 2097152
  float* out_w   = out + N_ROWS + N_ROWS * C_DIM;// 1048576

  char* ws = (char*)d_ws;
  _Float16* Ap  = (_Float16*)(ws);                         //  0 .. 4194304
  _Float16* Bp  = (_Float16*)(ws + 4194304);               //  .. 6291456
  float* xnorm  = (float*)(ws + 6291456);                  //  .. 6356992
  float* wnorm  = (float*)(ws + 6356992);                  //  .. 6389760
  float* pd1    = (float*)(ws + 6389760);                  // 4 MB
  float* pd2    = (float*)(ws + 10584064);                 // 4 MB
  unsigned* pc1 = (unsigned*)(ws + 14778368);              // 4 MB
  int* ids      = (int*)(ws + 18972672);                   // 64 KB
  int* fulll    = (int*)(ws + 19038208);                   // 64 KB
  unsigned* items = (unsigned*)(ws + 19103744);            // 1 MB
  unsigned* wnmax  = (unsigned*)(ws + 20152320);           // ctrl 16 B
  unsigned* icount = (unsigned*)(ws + 20152324);
  unsigned* fcount = (unsigned*)(ws + 20152328);
  unsigned* cnt    = (unsigned*)(ws + 20152336);           // 32 KB (int counts)
  unsigned* offs   = (unsigned*)(ws + 20185104);           // 32 KB
  unsigned* cursor = (unsigned*)(ws + 20217872);           // 32 KB
  unsigned long long* keys = (unsigned long long*)(ws + 20250640); // 128 KB
  int* rowlist  = (int*)(ws + 20381712);                   // 64 KB
  float* xT     = (float*)(ws + 20447248);                 // 8 MB .. 28835856
  (void)in_sizes; (void)n_in; (void)out_size; (void)ws_size;

  // zero ctrl + cnt (contiguous), 0xFF keys (sentinel ~0ull)
  hipMemsetAsync(ws + 20152320, 0, 16 + 32768, stream);
  hipMemsetAsync(ws + 20250640, 0xFF, N_ROWS * 8, stream);

  prep<<<384, 256, 0, stream>>>(enc, w, Ap, Bp, xT, xnorm, wnorm, wnmax);
  gemm_argmin<<<dim3(8, N_ROWS / 128), 512, 0, stream>>>(
      Ap, Bp, xnorm, wnorm, pd1, pc1, pd2);
  merge_classify<<<N_ROWS / 256, 256, 0, stream>>>(
      pd1, pc1, pd2, xnorm, wnmax, ids, items, icount, fulll, fcount);
  refine<<<2048, 256, 0, stream>>>(enc, w, wnorm, items, icount, fulll, fcount,
                                   keys);
  resolve_ids<<<N_ROWS / 256, 256, 0, stream>>>(keys, ids, cnt, out_ids);
  scan_offsets<<<1, 256, 0, stream>>>(cnt, offs, cursor);
  fill_rowlist<<<N_ROWS / 256, 256, 0, stream>>>(ids, cursor, rowlist);
  write_q<<<(N_ROWS * C_DIM) / 256, 256, 0, stream>>>(enc, w, ids, out_q);
  finalize_w<<<K_CODES / 4, 256, 0, stream>>>(w, xT, cnt, offs, rowlist, out_w);
}

// Round 11
// 279.401 us; speedup vs baseline: 2.0629x; 1.0827x over previous
//
#include <hip/hip_runtime.h>
#include <stdint.h>
#include <stddef.h>

// ---------------------------------------------------------------------------
// VQ-VAE quantizer, MI355X.  dist(n,k) = ||x||^2 + ||w_k||^2 - 2 x.w_k.
// f16 GEMM (KD=128), fragment-linear A/B, no LDS/barriers in K-loop.
// Refine (R4-proven): per-row threshold T = d1~ + 2E over 64 col-groups of
// 128 codes; group top-1s within T are candidates; any group top-2 within T
// -> exact full rescan.  Exact compares via u64 atomicMin keys.
// R11: gemm epilogue scan split into 8 independent top-2 chains + lex
// tournament (breaks the 480-cyc serial chain); keys/cnt init folded into
// merge_classify; write_q + finalize_w fused (qsum_final).
// ---------------------------------------------------------------------------

#define N_ROWS   16384      // B*H*W = 16*32*32
#define K_CODES  8192
#define C_DIM    128

typedef _Float16 f16x8 __attribute__((ext_vector_type(8)));
typedef float    f32x4 __attribute__((ext_vector_type(4)));

// ---------------- fused prep: blocks [0,256) pack x (+fp32 xT), [256,384) w
// Fragment-linear layout: half P[tile16 T=i>>4][kchunk C=c>>5][lane][8]
//   lane = (i&15) + 16*((c&31)>>3), elem j = c&7  (valid as MFMA A or B frag)
__global__ __launch_bounds__(256) void prep(const float* __restrict__ enc,
                                            const float* __restrict__ w,
                                            _Float16* __restrict__ Ap,
                                            _Float16* __restrict__ Bp,
                                            float* __restrict__ xT,
                                            float* __restrict__ xnorm,
                                            float* __restrict__ wnorm,
                                            unsigned* __restrict__ wnmax) {
  __shared__ float t[128][65];
  const int tid = threadIdx.x;
  if (blockIdx.x < 256) {                        // ---- x path
    const int b = blockIdx.x >> 4;
    const int hw0 = (blockIdx.x & 15) << 6;
    #pragma unroll
    for (int i = 0; i < 32; ++i) {
      int idx = i * 256 + tid;
      int c = idx >> 6, hwl = idx & 63;
      t[c][hwl] = enc[((size_t)(b * 128 + c) << 10) + hw0 + hwl];
    }
    __syncthreads();
    const int r = tid >> 2, sub = tid & 3;       // row-in-block, k-chunk
    const int n = (b << 10) + hw0 + r;
    const int R = n >> 4, m = n & 15;
    float s = 0.f;
    #pragma unroll
    for (int q = 0; q < 4; ++q) {
      f16x8 hv;
      float vv[8];
      #pragma unroll
      for (int e = 0; e < 8; ++e) {
        float v = t[sub * 32 + q * 8 + e][r];
        vv[e] = v;
        s += v * v;
        hv[e] = (_Float16)v;
      }
      *(f16x8*)(Ap + ((size_t)(R * 4 + sub) * 64 + (m + 16 * q)) * 8) = hv;
      *(float4*)(xT + (size_t)n * 128 + sub * 32 + q * 8) =
          (float4){vv[0], vv[1], vv[2], vv[3]};
      *(float4*)(xT + (size_t)n * 128 + sub * 32 + q * 8 + 4) =
          (float4){vv[4], vv[5], vv[6], vv[7]};
    }
    s += __shfl_xor(s, 1);
    s += __shfl_xor(s, 2);
    if (sub == 0) xnorm[n] = s;
  } else {                                       // ---- w path
    const int kk = (blockIdx.x - 256) * 64 + (tid >> 2), sub = tid & 3;
    const int R = kk >> 4, m = kk & 15;
    const float* base = w + (size_t)kk * C_DIM + sub * 32;
    float s = 0.f;
    #pragma unroll
    for (int q = 0; q < 4; ++q) {
      f16x8 hv;
      float4 va = *(const float4*)(base + q * 8);
      float4 vb = *(const float4*)(base + q * 8 + 4);
      float vv[8] = {va.x, va.y, va.z, va.w, vb.x, vb.y, vb.z, vb.w};
      #pragma unroll
      for (int e = 0; e < 8; ++e) { s += vv[e] * vv[e]; hv[e] = (_Float16)vv[e]; }
      *(f16x8*)(Bp + ((size_t)(R * 4 + sub) * 64 + (m + 16 * q)) * 8) = hv;
    }
    s += __shfl_xor(s, 1);
    s += __shfl_xor(s, 2);
    if (sub == 0) {
      wnorm[kk] = s;
      atomicMax(wnmax, __float_as_uint(s));      // s > 0 -> bit-monotone
    }
  }
}

// ---------------- main GEMM + per-(row,128col-group) top-2 -----------------
// Grid (8 colsplits, 128 rowblocks), 512 thr = 8 waves.  Wave tile: 16 rows
// (B operand) x 128 codes (8 A tiles) per group.  mfma(a=codes, b=rows):
// D col = lane&15 = x-row, D row = 4q+r = code.  Lane owns 1 row x 32 codes
// per group; scan = 8 independent 4-code top-2 chains + lex tournament
// (low chain depth), then 2-stage shfl_xor(16,32) reduce over q.
__global__ __launch_bounds__(512) void gemm_argmin(
    const _Float16* __restrict__ Ap, const _Float16* __restrict__ Bp,
    const float* __restrict__ xnorm, const float* __restrict__ wnorm,
    float* __restrict__ pd1, unsigned* __restrict__ pc1,
    float* __restrict__ pd2)
{
  const int tid = threadIdx.x;
  const int lane = tid & 63, wave = tid >> 6;    // 8 waves
  const int m = lane & 15, q = lane >> 4;
  const int cs = blockIdx.x;                     // col slice (1024 codes)
  const int row0 = blockIdx.y * 128;
  const int Tr = blockIdx.y * 8 + wave;          // wave's 16-row tile

  f16x8 bx[4];                                   // x-row fragments (invariant)
  #pragma unroll
  for (int kc = 0; kc < 4; ++kc)
    bx[kc] = *(const f16x8*)(Ap + (((size_t)Tr * 4 + kc) << 9) + (lane << 3));
  const float xn = xnorm[row0 + wave * 16 + m];  // this lane's x-row

  for (int it = 0; it < 8; ++it) {               // ascending col groups
    const int T0 = cs * 64 + it * 8;             // code-tile base
    const int g = cs * 8 + it;                   // group index [0,64)
    f32x4 acc[8];
    #pragma unroll
    for (int tj = 0; tj < 8; ++tj) acc[tj] = (f32x4){0.f, 0.f, 0.f, 0.f};
    #pragma unroll
    for (int kc = 0; kc < 4; ++kc) {
      #pragma unroll
      for (int tj = 0; tj < 8; ++tj) {
        f16x8 a = *(const f16x8*)(Bp + (((size_t)(T0 + tj) * 4 + kc) << 9) + (lane << 3));
        acc[tj] = __builtin_amdgcn_mfma_f32_16x16x32_f16(a, bx[kc], acc[tj], 0, 0, 0);
      }
    }
    // 8 independent 4-code top-2 chains (ascending code; strict < -> lowest)
    float td1[8], td2[8]; unsigned tc1[8];
    #pragma unroll
    for (int tj = 0; tj < 8; ++tj) {
      const int cb = (T0 + tj) * 16 + 4 * q;
      float4 wnq = *(const float4*)(wnorm + cb);
      float dd0 = fmaf(-2.0f, acc[tj][0], wnq.x);
      float dd1 = fmaf(-2.0f, acc[tj][1], wnq.y);
      float dd2 = fmaf(-2.0f, acc[tj][2], wnq.z);
      float dd3 = fmaf(-2.0f, acc[tj][3], wnq.w);
      float d1 = dd0, d2 = dd1; unsigned c1 = (unsigned)cb;
      if (dd1 < d1) { d2 = d1; d1 = dd1; c1 = (unsigned)(cb + 1); }
      if (dd2 < d1) { d2 = d1; d1 = dd2; c1 = (unsigned)(cb + 2); }
      else          { d2 = fminf(d2, dd2); }
      if (dd3 < d1) { d2 = d1; d1 = dd3; c1 = (unsigned)(cb + 3); }
      else          { d2 = fminf(d2, dd3); }
      td1[tj] = d1; td2[tj] = d2; tc1[tj] = c1;
    }
    // lex tournament 8 -> 1 (chains are ascending-code partitions)
    #pragma unroll
    for (int st = 1; st < 8; st <<= 1)
      #pragma unroll
      for (int j = 0; j < 8; j += 2 * st) {
        float o1 = td1[j + st], o2 = td2[j + st]; unsigned oc = tc1[j + st];
        float n2 = fminf(fminf(td2[j], o2), fmaxf(td1[j], o1));
        if (o1 < td1[j] || (o1 == td1[j] && oc < tc1[j])) { td1[j] = o1; tc1[j] = oc; }
        td2[j] = n2;
      }
    float d1 = td1[0], d2 = td2[0]; unsigned c1 = tc1[0];
    // reduce across q (lanes differing in bits 4,5); lex (d,c) tie rule
    #pragma unroll
    for (int s = 16; s <= 32; s <<= 1) {
      float    od1 = __shfl_xor(d1, s), od2 = __shfl_xor(d2, s);
      unsigned oc1 = (unsigned)__shfl_xor((int)c1, s);
      float nd2 = fminf(fminf(d2, od2), fmaxf(d1, od1));
      if (od1 < d1 || (od1 == d1 && oc1 < c1)) { d1 = od1; c1 = oc1; }
      d2 = nd2;
    }
    if (q == 0) {
      int row = row0 + wave * 16 + m;
      size_t pi = (size_t)g * N_ROWS + row;
      pd1[pi] = xn + d1; pc1[pi] = c1; pd2[pi] = xn + d2;
    }
  }
}

// ---------------- classify: threshold-collect over 64 groups ---------------
// Also initializes keys[] (sentinel) and cnt[] (zeros) for later kernels.
__global__ void merge_classify(const float* __restrict__ pd1,
                               const unsigned* __restrict__ pc1,
                               const float* __restrict__ pd2,
                               const float* __restrict__ xnorm,
                               const unsigned* __restrict__ wnmax,
                               int* __restrict__ ids,
                               unsigned* __restrict__ items,
                               unsigned* __restrict__ icount,
                               int* __restrict__ fulll,
                               unsigned* __restrict__ fcount,
                               unsigned long long* __restrict__ keys,
                               unsigned* __restrict__ cnt) {
  int row = blockIdx.x * 256 + threadIdx.x;
  keys[row] = ~0ull;                             // init for refine/resolve
  if (row < K_CODES) cnt[row] = 0u;
  float da = __builtin_inff(), db = __builtin_inff(),
        dc = __builtin_inff(), dd = __builtin_inff();
  unsigned ca = 0, cb_ = 0, cc = 0, cd = 0;
  for (int cb = 0; cb < 64; cb += 4) {
    size_t i0 = (size_t)cb * N_ROWS + row;
    float va = pd1[i0], vb = pd1[i0 + (size_t)N_ROWS],
          vc = pd1[i0 + 2 * (size_t)N_ROWS], vd = pd1[i0 + 3 * (size_t)N_ROWS];
    unsigned ka = pc1[i0], kb = pc1[i0 + (size_t)N_ROWS],
             kc = pc1[i0 + 2 * (size_t)N_ROWS], kd = pc1[i0 + 3 * (size_t)N_ROWS];
    if (va < da || (va == da && ka < ca)) { da = va; ca = ka; }
    if (vb < db || (vb == db && kb < cb_)) { db = vb; cb_ = kb; }
    if (vc < dc || (vc == dc && kc < cc)) { dc = vc; cc = kc; }
    if (vd < dd || (vd == dd && kd < cd)) { dd = vd; cd = kd; }
  }
  float d1 = da; unsigned c1 = ca;
  if (db < d1 || (db == d1 && cb_ < c1)) { d1 = db; c1 = cb_; }
  if (dc < d1 || (dc == d1 && cc < c1)) { d1 = dc; c1 = cc; }
  if (dd < d1 || (dd == d1 && cd < c1)) { d1 = dd; c1 = cd; }

  float wm = __uint_as_float(*wnmax);
  float twoE = 2.0f * (0.0029297f * sqrtf(xnorm[row] * wm) + 2e-4f);
  float T = d1 + twoE;
  bool full = false;
  int nc = 0;
  unsigned cands[6];
  #pragma unroll 4
  for (int cb = 0; cb < 64; ++cb) {
    size_t i = (size_t)cb * N_ROWS + row;
    if (pd2[i] <= T) { full = true; }
    else if (pd1[i] <= T) {
      if (nc < 6) cands[nc++] = pc1[i];
      else full = true;
    }
  }
  ids[row] = (int)c1;                            // exact if nc==1 && !full
  if (full) {
    unsigned fi = atomicAdd(fcount, 1u);
    fulll[fi] = row;
  } else if (nc >= 2) {
    unsigned base = atomicAdd(icount, (unsigned)nc);
    for (int i = 0; i < nc; ++i)
      items[base + i] = ((unsigned)row << 13) | cands[i];
  }
}

// ---------------- fused exact refine: items (phase A) + full (phase B) -----
__global__ __launch_bounds__(256) void refine(
    const float* __restrict__ enc, const float* __restrict__ w,
    const float* __restrict__ wnorm,
    const unsigned* __restrict__ items, const unsigned* __restrict__ icount,
    const int* __restrict__ fulll, const unsigned* __restrict__ fcount,
    unsigned long long* __restrict__ keys) {
  const int tid = threadIdx.x;
  const int lane = tid & 63, wave = tid >> 6;
  // ---- phase A: candidate items
  const unsigned ic = *icount;
  for (unsigned i = blockIdx.x * 256 + tid; i < ic; i += gridDim.x * 256) {
    unsigned it = items[i];
    int row = (int)(it >> 13), c = (int)(it & 8191u);
    int b = row >> 10, hw = row & 1023;
    const float* xb = enc + ((size_t)b << 17) + hw;
    const float* wk = w + (size_t)c * C_DIM;
    float xn = 0.f, s = 0.f;
    for (int cc = 0; cc < C_DIM; ++cc) {
      float x = xb[(size_t)cc << 10];
      xn += x * x;
      s = fmaf(x, wk[cc], s);
    }
    float d = (xn + wnorm[c]) - 2.0f * s;
    unsigned sb = __float_as_uint(d);
    sb = (sb >> 31) ? ~sb : (sb | 0x80000000u);  // sortable float bits
    unsigned long long key = ((unsigned long long)sb << 32) | (unsigned)c;
    atomicMin(&keys[row], key);                  // tie -> lowest code
  }
  // ---- phase B: full rescans, sliced over the codebook
  __shared__ __align__(16) float xs[128];
  __shared__ unsigned long long red[4];
  const unsigned nitems = *fcount * 8;
  for (unsigned item = blockIdx.x; item < nitems; item += gridDim.x) {
    const int row = fulll[item >> 3];
    const int slice = (int)(item & 7u);
    if (tid < 128)                               // stage x row
      xs[tid] = enc[(((size_t)(row >> 10) * 128 + tid) << 10) + (row & 1023)];
    __syncthreads();
    float xn = 0.f;                              // serial order (R4-identical)
    for (int c = 0; c < 128; ++c) xn += xs[c] * xs[c];
    const int k0 = slice * 1024 + tid * 4;
    float S[4];
    #pragma unroll
    for (int j = 0; j < 4; ++j) S[j] = 0.f;
    for (int c4 = 0; c4 < 32; ++c4) {
      float4 xv = *(const float4*)(&xs[c4 * 4]);
      #pragma unroll
      for (int j = 0; j < 4; ++j) {
        float4 wv = *(const float4*)(w + (size_t)(k0 + j) * C_DIM + c4 * 4);
        S[j] = fmaf(xv.x, wv.x, S[j]);
        S[j] = fmaf(xv.y, wv.y, S[j]);
        S[j] = fmaf(xv.z, wv.z, S[j]);
        S[j] = fmaf(xv.w, wv.w, S[j]);
      }
    }
    unsigned long long best = ~0ull;
    #pragma unroll
    for (int j = 0; j < 4; ++j) {
      float d = (xn + wnorm[k0 + j]) - 2.0f * S[j];
      unsigned sb = __float_as_uint(d);
      sb = (sb >> 31) ? ~sb : (sb | 0x80000000u);
      unsigned long long key = ((unsigned long long)sb << 32) | (unsigned)(k0 + j);
      best = best < key ? best : key;
    }
    #pragma unroll
    for (int s = 1; s <= 32; s <<= 1) {          // 64-lane u64 butterfly
      unsigned long long ok = __shfl_xor(best, s);
      best = ok < best ? ok : best;
    }
    if (lane == 0) red[wave] = best;
    __syncthreads();
    if (tid == 0) {
      unsigned long long bk = red[0];
      #pragma unroll
      for (int wv = 1; wv < 4; ++wv) bk = red[wv] < bk ? red[wv] : bk;
      atomicMin(&keys[row], bk);
    }
    __syncthreads();                             // xs reused next item
  }
}

// ---------------- resolve final ids + int counts + out_ids -----------------
__global__ void resolve_ids(const unsigned long long* __restrict__ keys,
                            int* __restrict__ ids, unsigned* __restrict__ cnt,
                            float* __restrict__ out_ids) {
  int row = blockIdx.x * 256 + threadIdx.x;
  unsigned long long k = keys[row];
  int id = (k != ~0ull) ? (int)(unsigned)(k & 0xffffffffu) : ids[row];
  ids[row] = id;
  out_ids[row] = (float)id;
  atomicAdd(&cnt[id], 1u);
}

// ---------------- exclusive scan of counts -> offs + cursor (1 block) ------
__global__ __launch_bounds__(256) void scan_offsets(
    const unsigned* __restrict__ cnt,
    unsigned* __restrict__ offs, unsigned* __restrict__ cursor) {
  __shared__ unsigned tot[256];
  const int tid = threadIdx.x;
  unsigned local[32], run = 0;
  #pragma unroll
  for (int i = 0; i < 32; ++i) { local[i] = run; run += cnt[tid * 32 + i]; }
  tot[tid] = run;
  __syncthreads();
  for (int st = 1; st < 256; st <<= 1) {
    unsigned v = (tid >= st) ? tot[tid - st] : 0u;
    __syncthreads();
    tot[tid] += v;
    __syncthreads();
  }
  unsigned excl = (tid == 0) ? 0u : tot[tid - 1];
  #pragma unroll
  for (int i = 0; i < 32; ++i) {
    unsigned o = excl + local[i];
    offs[tid * 32 + i] = o;
    cursor[tid * 32 + i] = o;
  }
}

// ---------------- fill CSR row list ----------------------------------------
__global__ void fill_rowlist(const int* __restrict__ ids,
                             unsigned* __restrict__ cursor,
                             int* __restrict__ rowlist) {
  int row = blockIdx.x * 256 + threadIdx.x;
  unsigned slot = atomicAdd(&cursor[ids[row]], 1u);
  rowlist[slot] = row;
}

// ---------------- fused tail: q (blocks<8192) + EMA gather (rest) ----------
__global__ __launch_bounds__(256) void qsum_final(
    const float* __restrict__ enc, const float* __restrict__ w,
    const int* __restrict__ ids,
    const unsigned* __restrict__ cnt, const unsigned* __restrict__ offs,
    const int* __restrict__ rowlist, const float* __restrict__ xT,
    float* __restrict__ outq, float* __restrict__ outw) {
  if (blockIdx.x < 8192) {                       // ---- straight-through q
    int e = blockIdx.x * 256 + threadIdx.x;      // linear over enc [B,C,H,W]
    int c = (e >> 10) & 127;
    int b = e >> 17;
    int n = (b << 10) | (e & 1023);
    float x = enc[e];
    float wq = w[(size_t)ids[n] * C_DIM + c];
    outq[e] = x + (wq - x);                      // reference rounding order
  } else {                                       // ---- EMA gather, wave/code
    const int tid = threadIdx.x;
    const int lane = tid & 63, wave = tid >> 6;
    const int k = (int)(blockIdx.x - 8192) * 4 + wave;
    const unsigned n0 = offs[k], nk = cnt[k];
    float S0a = 0.f, S0b = 0.f, S0c = 0.f, S0d = 0.f;
    float S1a = 0.f, S1b = 0.f, S1c = 0.f, S1d = 0.f;
    unsigned i = 0;
    for (; i + 4 <= nk; i += 4) {                // 4-way ILP partial sums
      int r0 = rowlist[n0 + i],     r1 = rowlist[n0 + i + 1];
      int r2 = rowlist[n0 + i + 2], r3 = rowlist[n0 + i + 3];
      S0a += xT[(size_t)r0 * 128 + lane];      S1a += xT[(size_t)r0 * 128 + lane + 64];
      S0b += xT[(size_t)r1 * 128 + lane];      S1b += xT[(size_t)r1 * 128 + lane + 64];
      S0c += xT[(size_t)r2 * 128 + lane];      S1c += xT[(size_t)r2 * 128 + lane + 64];
      S0d += xT[(size_t)r3 * 128 + lane];      S1d += xT[(size_t)r3 * 128 + lane + 64];
    }
    for (; i < nk; ++i) {
      int r = rowlist[n0 + i];
      S0a += xT[(size_t)r * 128 + lane];
      S1a += xT[(size_t)r * 128 + lane + 64];
    }
    float S0 = (S0a + S0b) + (S0c + S0d);
    float S1 = (S1a + S1b) + (S1c + S1d);
    const float omd = (float)(1.0 - 0.99);
    float cf = (float)nk + 1e-12f;
    outw[(size_t)k * 128 + lane]      = 0.99f * w[(size_t)k * 128 + lane]      + omd * (S0 / cf);
    outw[(size_t)k * 128 + lane + 64] = 0.99f * w[(size_t)k * 128 + lane + 64] + omd * (S1 / cf);
  }
}

// ---------------------------------------------------------------------------
extern "C" void kernel_launch(void* const* d_in, const int* in_sizes, int n_in,
                              void* d_out, int out_size, void* d_ws, size_t ws_size,
                              hipStream_t stream) {
  const float* enc = (const float*)d_in[0];      // [16,128,32,32]
  const float* w   = (const float*)d_in[1];      // [8192,128]
  float* out = (float*)d_out;
  float* out_ids = out;                          // 16384 (ids as float)
  float* out_q   = out + N_ROWS;                 // 2097152
  float* out_w   = out + N_ROWS + N_ROWS * C_DIM;// 1048576

  char* ws = (char*)d_ws;
  _Float16* Ap  = (_Float16*)(ws);                         //  0 .. 4194304
  _Float16* Bp  = (_Float16*)(ws + 4194304);               //  .. 6291456
  float* xnorm  = (float*)(ws + 6291456);                  //  .. 6356992
  float* wnorm  = (float*)(ws + 6356992);                  //  .. 6389760
  float* pd1    = (float*)(ws + 6389760);                  // 4 MB
  float* pd2    = (float*)(ws + 10584064);                 // 4 MB
  unsigned* pc1 = (unsigned*)(ws + 14778368);              // 4 MB
  int* ids      = (int*)(ws + 18972672);                   // 64 KB
  int* fulll    = (int*)(ws + 19038208);                   // 64 KB
  unsigned* items = (unsigned*)(ws + 19103744);            // 1 MB
  unsigned* wnmax  = (unsigned*)(ws + 20152320);           // ctrl 16 B
  unsigned* icount = (unsigned*)(ws + 20152324);
  unsigned* fcount = (unsigned*)(ws + 20152328);
  unsigned* cnt    = (unsigned*)(ws + 20152336);           // 32 KB (int counts)
  unsigned* offs   = (unsigned*)(ws + 20185104);           // 32 KB
  unsigned* cursor = (unsigned*)(ws + 20217872);           // 32 KB
  unsigned long long* keys = (unsigned long long*)(ws + 20250640); // 128 KB
  int* rowlist  = (int*)(ws + 20381712);                   // 64 KB
  float* xT     = (float*)(ws + 20447248);                 // 8 MB .. 28835856
  (void)in_sizes; (void)n_in; (void)out_size; (void)ws_size;

  // zero ctrl only (wnmax/icount/fcount); keys+cnt init in merge_classify
  hipMemsetAsync(ws + 20152320, 0, 16, stream);

  prep<<<384, 256, 0, stream>>>(enc, w, Ap, Bp, xT, xnorm, wnorm, wnmax);
  gemm_argmin<<<dim3(8, N_ROWS / 128), 512, 0, stream>>>(
      Ap, Bp, xnorm, wnorm, pd1, pc1, pd2);
  merge_classify<<<N_ROWS / 256, 256, 0, stream>>>(
      pd1, pc1, pd2, xnorm, wnmax, ids, items, icount, fulll, fcount, keys, cnt);
  refine<<<2048, 256, 0, stream>>>(enc, w, wnorm, items, icount, fulll, fcount,
                                   keys);
  resolve_ids<<<N_ROWS / 256, 256, 0, stream>>>(keys, ids, cnt, out_ids);
  scan_offsets<<<1, 256, 0, stream>>>(cnt, offs, cursor);
  fill_rowlist<<<N_ROWS / 256, 256, 0, stream>>>(ids, cursor, rowlist);
  qsum_final<<<8192 + K_CODES / 4, 256, 0, stream>>>(
      enc, w, ids, cnt, offs, rowlist, xT, out_q, out_w);
}